// Round 4
// baseline (207.572 us; speedup 1.0000x reference)
//
#include <hip/hip_runtime.h>
#include <math.h>

#define B_  8
#define C_  384
#define NS_ 1024
#define HEADS_ 12
#define HD_ 32
#define GROUPS_ 3
#define CG_ 128
#define EPS_ 1e-5f
// 1/sqrt(32) * log2(e)  (exp computed as exp2)
#define QSC2 (0.17677669529663687f * 1.4426950408889634f)

typedef __attribute__((ext_vector_type(8))) short bf16x8;
typedef __attribute__((ext_vector_type(4))) short bf16x4;
typedef __attribute__((ext_vector_type(4))) float f32x4;
typedef __attribute__((ext_vector_type(8))) __bf16 b8;

static __device__ __forceinline__ short f2b(float f) {
  union { float f; unsigned u; } v; v.f = f;
  unsigned r = v.u + 0x7fffu + ((v.u >> 16) & 1u);   // RNE
  return (short)(r >> 16);
}
static __device__ __forceinline__ float b2f(short s) {
  union { unsigned u; float f; } v; v.u = ((unsigned)(unsigned short)s) << 16;
  return v.f;
}

#if __has_builtin(__builtin_amdgcn_exp2f)
#define EXP2(x) __builtin_amdgcn_exp2f(x)
#else
#define EXP2(x) exp2f(x)
#endif

static __device__ __forceinline__ unsigned cvtpk(float lo, float hi) {
  unsigned r;
  asm("v_cvt_pk_bf16_f32 %0, %1, %2" : "=v"(r) : "v"(lo), "v"(hi));
  return r;
}

static __device__ __forceinline__ f32x4 MFMA(bf16x8 a, bf16x8 b, f32x4 c) {
  return __builtin_amdgcn_mfma_f32_16x16x32_bf16(
      __builtin_bit_cast(b8, a), __builtin_bit_cast(b8, b), c, 0, 0, 0);
}

// ---------------------------------------------------------------------------
// weight fp32 -> bf16 (4 matrices)
// ---------------------------------------------------------------------------
__global__ void convw(const float* __restrict__ s0, const float* __restrict__ s1,
                      const float* __restrict__ s2, const float* __restrict__ s3,
                      short* __restrict__ d0, short* __restrict__ d1,
                      short* __restrict__ d2, short* __restrict__ d3, int n) {
  int i = blockIdx.x * 256 + threadIdx.x;
  if (i >= n) return;
  const float* s = blockIdx.y == 0 ? s0 : blockIdx.y == 1 ? s1 : blockIdx.y == 2 ? s2 : s3;
  short*       d = blockIdx.y == 0 ? d0 : blockIdx.y == 1 ? d1 : blockIdx.y == 2 ? d2 : d3;
  d[i] = f2b(s[i]);
}

// ---------------------------------------------------------------------------
// x1 (B,C,NS) f32 -> x1t (B,NS,C) bf16
// ---------------------------------------------------------------------------
__global__ __launch_bounds__(256) void transp(const float* __restrict__ src,
                                              short* __restrict__ dst) {
  __shared__ float tl[32][33];
  int n0 = blockIdx.x * 32, c0 = blockIdx.y * 32, b = blockIdx.z;
  int tx = threadIdx.x & 31, ty = threadIdx.x >> 5;
#pragma unroll
  for (int i = 0; i < 4; ++i)
    tl[ty + 8 * i][tx] = src[((size_t)b * C_ + c0 + ty + 8 * i) * NS_ + n0 + tx];
  __syncthreads();
#pragma unroll
  for (int i = 0; i < 4; ++i)
    dst[((size_t)b * NS_ + n0 + ty + 8 * i) * C_ + c0 + tx] = f2b(tl[tx][ty + 8 * i]);
}

// ---------------------------------------------------------------------------
// MFMA GEMM, 64x64 block tile (4 waves, 32x32/wave, acc 2x2), K fully unrolled.
// MODE 0: out n-major bf16            (k projection)
// MODE 1: outf d-major f32, outb n-major bf16 * QSC2    (q projection)
// MODE 2: out d-major bf16            (v projection)
// MODE 3: outf d-major f32 + res      (final projection + residual)
// ---------------------------------------------------------------------------
template <int MODE>
__global__ __launch_bounds__(256) void gemm_nm(
    const short* __restrict__ A, const short* __restrict__ Wb,
    const float* __restrict__ bias, const float* __restrict__ res,
    short* __restrict__ outb, float* __restrict__ outf) {
  int b = blockIdx.z;
  int n0 = blockIdx.x * 64;
  int m0 = blockIdx.y * 64;
  int wv = threadIdx.x >> 6;
  int lane = threadIdx.x & 63;
  int g = lane >> 4, r15 = lane & 15;
  int wr = (wv >> 1) * 32, wc = (wv & 1) * 32;

  const short* Ab = A + (size_t)b * NS_ * C_;
  f32x4 acc[2][2];
#pragma unroll
  for (int i = 0; i < 2; ++i)
#pragma unroll
    for (int j = 0; j < 2; ++j) acc[i][j] = (f32x4){0.f, 0.f, 0.f, 0.f};

#pragma unroll
  for (int kc = 0; kc < C_; kc += 32) {
    bf16x8 af[2], bfr[2];
#pragma unroll
    for (int rt = 0; rt < 2; ++rt)
      af[rt] = *(const bf16x8*)(Ab + (size_t)(n0 + wr + rt * 16 + r15) * C_ + kc + g * 8);
#pragma unroll
    for (int ct = 0; ct < 2; ++ct)
      bfr[ct] = *(const bf16x8*)(Wb + (size_t)(m0 + wc + ct * 16 + r15) * C_ + kc + g * 8);
#pragma unroll
    for (int rt = 0; rt < 2; ++rt)
#pragma unroll
      for (int ct = 0; ct < 2; ++ct) acc[rt][ct] = MFMA(af[rt], bfr[ct], acc[rt][ct]);
  }

#pragma unroll
  for (int rt = 0; rt < 2; ++rt)
#pragma unroll
    for (int ct = 0; ct < 2; ++ct) {
      int m = m0 + wc + ct * 16 + r15;
      int nb = n0 + wr + rt * 16 + g * 4;
      float bv = bias[m];
      f32x4 v = acc[rt][ct];
      v.x += bv; v.y += bv; v.z += bv; v.w += bv;
      if (MODE == 1) {
        *(f32x4*)(outf + ((size_t)b * C_ + m) * NS_ + nb) = v;
        outb[((size_t)b * NS_ + nb + 0) * C_ + m] = f2b(v.x * QSC2);
        outb[((size_t)b * NS_ + nb + 1) * C_ + m] = f2b(v.y * QSC2);
        outb[((size_t)b * NS_ + nb + 2) * C_ + m] = f2b(v.z * QSC2);
        outb[((size_t)b * NS_ + nb + 3) * C_ + m] = f2b(v.w * QSC2);
      } else if (MODE == 0) {
        outb[((size_t)b * NS_ + nb + 0) * C_ + m] = f2b(v.x);
        outb[((size_t)b * NS_ + nb + 1) * C_ + m] = f2b(v.y);
        outb[((size_t)b * NS_ + nb + 2) * C_ + m] = f2b(v.z);
        outb[((size_t)b * NS_ + nb + 3) * C_ + m] = f2b(v.w);
      } else if (MODE == 2) {
        bf16x4 s4 = {f2b(v.x), f2b(v.y), f2b(v.z), f2b(v.w)};
        *(bf16x4*)(outb + ((size_t)b * C_ + m) * NS_ + nb) = s4;
      } else {
        const f32x4 rv = *(const f32x4*)(res + ((size_t)b * C_ + m) * NS_ + nb);
        v.x += rv.x; v.y += rv.y; v.z += rv.z; v.w += rv.w;
        *(f32x4*)(outf + ((size_t)b * C_ + m) * NS_ + nb) = v;
      }
    }
}

// ---------------------------------------------------------------------------
// fused depthwise 5x5 + LN + GELU + offset proj + bilinear sample (unchanged)
// ---------------------------------------------------------------------------
__global__ __launch_bounds__(256) void offsample3(
    const float* __restrict__ qd, const float* __restrict__ x2,
    const float* __restrict__ dw, const float* __restrict__ dwb,
    const float* __restrict__ lng, const float* __restrict__ lnb,
    const float* __restrict__ offw, short* __restrict__ samp) {
  __shared__ float redS[4][16], redSS[4][16], redO0[4][16], redO1[4][16];
  int bg = blockIdx.x, t16 = blockIdx.y;
  int tid = threadIdx.x;
  int cc = tid >> 4, p = tid & 15;
  int wv = tid >> 6, lane = tid & 63;
  int n = t16 * 16 + p;
  int y = t16 >> 1;
  int x = ((t16 & 1) << 4) + p;
  int c0 = cc << 3;

  const float* qb = qd + (size_t)bg * CG_ * NS_;

  float a[8];
  float s = 0.f, ss = 0.f;
#pragma unroll 2
  for (int i = 0; i < 8; ++i) {
    int c = c0 + i;
    const float* qc = qb + (size_t)c * NS_;
    const float* wc = dw + c * 25;
    float acc = dwb[c];
#pragma unroll
    for (int dy = -2; dy <= 2; ++dy) {
      int yy = y + dy;
      if (yy < 0 || yy > 31) continue;
      const float* row = qc + yy * 32;
      const float* wr_ = wc + (dy + 2) * 5;
#pragma unroll
      for (int dx = -2; dx <= 2; ++dx) {
        int xx = x + dx;
        int xcl = min(max(xx, 0), 31);
        float v = row[xcl];
        if (xx != xcl) v = 0.f;
        acc = fmaf(v, wr_[dx + 2], acc);
      }
    }
    a[i] = acc;
    s += acc; ss += acc * acc;
  }

  s  += __shfl_xor(s, 16);  s  += __shfl_xor(s, 32);
  ss += __shfl_xor(ss, 16); ss += __shfl_xor(ss, 32);
  if (lane < 16) { redS[wv][lane] = s; redSS[wv][lane] = ss; }
  __syncthreads();
  float S  = (redS[0][p]  + redS[1][p])  + (redS[2][p]  + redS[3][p]);
  float SS = (redSS[0][p] + redSS[1][p]) + (redSS[2][p] + redSS[3][p]);
  float mu = S * (1.f / CG_);
  float var = SS * (1.f / CG_) - mu * mu;
  float rs = rsqrtf(var + EPS_);

  float o0 = 0.f, o1 = 0.f;
#pragma unroll
  for (int i = 0; i < 8; ++i) {
    int c = c0 + i;
    float z = (a[i] - mu) * rs * lng[c] + lnb[c];
    float u = z * fmaf(0.044715f * z, z, 1.f);
    float e = __expf(-1.5957691216057308f * u);
    float ge = z * __builtin_amdgcn_rcpf(1.f + e);
    o0 = fmaf(offw[c], ge, o0);
    o1 = fmaf(offw[CG_ + c], ge, o1);
  }
  o0 += __shfl_xor(o0, 16); o0 += __shfl_xor(o0, 32);
  o1 += __shfl_xor(o1, 16); o1 += __shfl_xor(o1, 32);
  if (lane < 16) { redO0[wv][lane] = o0; redO1[wv][lane] = o1; }
  __syncthreads();
  float off0 = (redO0[0][p] + redO0[1][p]) + (redO0[2][p] + redO0[3][p]);
  float off1 = (redO1[0][p] + redO1[1][p]) + (redO1[2][p] + redO1[3][p]);

  float gx = (x + 0.5f) * 0.0625f - 1.f;
  float gy = (y + 0.5f) * 0.0625f - 1.f;
  float px = fminf(fmaxf(off0 + gx, -1.f), 1.f);
  float py = fminf(fmaxf(off1 + gy, -1.f), 1.f);
  float ix = (px + 1.f) * 0.5f * 31.f;
  float iy = (py + 1.f) * 0.5f * 31.f;
  float x0f = floorf(ix), y0f = floorf(iy);
  float wx = ix - x0f, wy = iy - y0f;
  int x0 = min(max((int)x0f, 0), 31), x1i = min(x0 + 1, 31);
  int y0 = min(max((int)y0f, 0), 31), y1i = min(y0 + 1, 31);
  int i00 = y0 * 32 + x0,  i01 = y0 * 32 + x1i;
  int i10 = y1i * 32 + x0, i11 = y1i * 32 + x1i;
  float w00 = (1.f - wx) * (1.f - wy), w01 = wx * (1.f - wy);
  float w10 = (1.f - wx) * wy,         w11 = wx * wy;

  int b = bg / GROUPS_, gi = bg % GROUPS_;
  const float* xb = x2 + (size_t)bg * CG_ * NS_;
  short out8[8];
#pragma unroll
  for (int i = 0; i < 8; ++i) {
    const float* xc = xb + (size_t)(c0 + i) * NS_;
    float v = w00 * xc[i00] + w01 * xc[i01] + w10 * xc[i10] + w11 * xc[i11];
    out8[i] = f2b(v);
  }
  *(bf16x8*)(samp + ((size_t)b * NS_ + n) * C_ + gi * CG_ + c0) = *(bf16x8*)out8;
}

// ---------------------------------------------------------------------------
// Split-K MFMA attention, no-max softmax (scores |s|<~1, statically safe).
// wave = 32 queries x 512 keys. Partial o (raw, bf16) + l (f32) per split.
// q_nC prescaled by QSC2 so p = exp2(S).
// ---------------------------------------------------------------------------
__global__ __launch_bounds__(256) void attn_split(
    const short* __restrict__ qn, const short* __restrict__ kn,
    const short* __restrict__ vd, short* __restrict__ op0,
    short* __restrict__ op1, float* __restrict__ lp) {
  int by = blockIdx.y;
  int bh = by >> 1, s = by & 1;
  int b = bh / HEADS_, h = bh % HEADS_;
  int wv = threadIdx.x >> 6, lane = threadIdx.x & 63;
  int g = lane >> 4, q15 = lane & 15;
  int q0 = blockIdx.x * 128 + wv * 32;

  const short* Qb = qn + (size_t)b * NS_ * C_ + h * HD_;
  const short* Kb = kn + ((size_t)b * NS_ + s * 512) * C_ + h * HD_;
  const short* Vb = vd + ((size_t)b * C_ + h * HD_) * NS_ + s * 512;

  bf16x8 qf[2];
  qf[0] = *(const bf16x8*)(Qb + (size_t)(q0 + q15) * C_ + g * 8);
  qf[1] = *(const bf16x8*)(Qb + (size_t)(q0 + 16 + q15) * C_ + g * 8);

  f32x4 o[2][2];
  o[0][0] = o[0][1] = o[1][0] = o[1][1] = (f32x4){0.f, 0.f, 0.f, 0.f};
  f32x4 lv[2];
  lv[0] = lv[1] = (f32x4){0.f, 0.f, 0.f, 0.f};

#pragma unroll
  for (int c = 0; c < 16; ++c) {
    int k0 = c * 32;
    bf16x8 kf0 = *(const bf16x8*)(Kb + (size_t)(k0 + q15) * C_ + g * 8);
    bf16x8 kf1 = *(const bf16x8*)(Kb + (size_t)(k0 + 16 + q15) * C_ + g * 8);
    bf16x8 vf[2];
#pragma unroll
    for (int dt = 0; dt < 2; ++dt) {
      const short* vp = Vb + (size_t)(dt * 16 + q15) * NS_ + k0 + g * 4;
      bf16x4 lo = *(const bf16x4*)(vp);
      bf16x4 hi = *(const bf16x4*)(vp + 16);
      vf[dt] = (bf16x8){lo.x, lo.y, lo.z, lo.w, hi.x, hi.y, hi.z, hi.w};
    }
#pragma unroll
    for (int qt = 0; qt < 2; ++qt) {
      f32x4 z = {0.f, 0.f, 0.f, 0.f};
      f32x4 t0 = MFMA(kf0, qf[qt], z);
      f32x4 t1 = MFMA(kf1, qf[qt], z);
      f32x4 e0, e1;
      e0.x = EXP2(t0.x); e0.y = EXP2(t0.y); e0.z = EXP2(t0.z); e0.w = EXP2(t0.w);
      e1.x = EXP2(t1.x); e1.y = EXP2(t1.y); e1.z = EXP2(t1.z); e1.w = EXP2(t1.w);
      lv[qt] += e0; lv[qt] += e1;
      union { unsigned u[4]; bf16x8 v; } pu;
      pu.u[0] = cvtpk(e0.x, e0.y);
      pu.u[1] = cvtpk(e0.z, e0.w);
      pu.u[2] = cvtpk(e1.x, e1.y);
      pu.u[3] = cvtpk(e1.z, e1.w);
      o[qt][0] = MFMA(vf[0], pu.v, o[qt][0]);
      o[qt][1] = MFMA(vf[1], pu.v, o[qt][1]);
    }
  }

  short* opS = s ? op1 : op0;
#pragma unroll
  for (int qt = 0; qt < 2; ++qt) {
    float lt = (lv[qt].x + lv[qt].y) + (lv[qt].z + lv[qt].w);
    lt += __shfl_xor(lt, 16);
    lt += __shfl_xor(lt, 32);
    int q = q0 + qt * 16 + q15;
    if (g == 0) lp[((size_t)(s * B_ + b) * HEADS_ + h) * NS_ + q] = lt;
#pragma unroll
    for (int dt = 0; dt < 2; ++dt) {
      f32x4 ov = o[qt][dt];
      bf16x4 s4 = {f2b(ov.x), f2b(ov.y), f2b(ov.z), f2b(ov.w)};
      *(bf16x4*)(opS + ((size_t)b * NS_ + q) * C_ + h * HD_ + dt * 16 + g * 4) = s4;
    }
  }
}

// ---------------------------------------------------------------------------
// merge: o = (op0 + op1) / (l0 + l1), out n-major bf16
// ---------------------------------------------------------------------------
__global__ __launch_bounds__(256) void attn_merge(
    const short* __restrict__ op0, const short* __restrict__ op1,
    const float* __restrict__ lp, short* __restrict__ on) {
  int idx = blockIdx.x * 256 + threadIdx.x;    // B*NS*48 chunks of 8
  int c8 = idx % (C_ / 8);
  int q  = (idx / (C_ / 8)) % NS_;
  int b  = idx / ((C_ / 8) * NS_);
  int c0 = c8 * 8, h = c0 >> 5;
  size_t off = ((size_t)b * NS_ + q) * C_ + c0;
  bf16x8 a  = *(const bf16x8*)(op0 + off);
  bf16x8 bb = *(const bf16x8*)(op1 + off);
  float l = lp[((size_t)b * HEADS_ + h) * NS_ + q] +
            lp[((size_t)(B_ + b) * HEADS_ + h) * NS_ + q];
  float rl = 1.f / l;
  short r[8];
#pragma unroll
  for (int j = 0; j < 8; ++j) r[j] = f2b((b2f(a[j]) + b2f(bb[j])) * rl);
  *(bf16x8*)(on + off) = *(bf16x8*)r;
}

// ---------------------------------------------------------------------------
extern "C" void kernel_launch(void* const* d_in, const int* in_sizes, int n_in,
                              void* d_out, int out_size, void* d_ws, size_t ws_size,
                              hipStream_t stream) {
  const float* x1      = (const float*)d_in[0];
  const float* x2      = (const float*)d_in[1];
  const float* Wq      = (const float*)d_in[2];
  const float* bq      = (const float*)d_in[3];
  const float* Wk      = (const float*)d_in[4];
  const float* bk      = (const float*)d_in[5];
  const float* Wv      = (const float*)d_in[6];
  const float* bv      = (const float*)d_in[7];
  const float* Wo      = (const float*)d_in[8];
  const float* bo      = (const float*)d_in[9];
  const float* off_dw  = (const float*)d_in[10];
  const float* off_dwb = (const float*)d_in[11];
  const float* ln_g    = (const float*)d_in[12];
  const float* ln_b    = (const float*)d_in[13];
  const float* off_w   = (const float*)d_in[14];

  char* base = (char*)d_ws;
  const size_t SZ = (size_t)B_ * C_ * NS_;
  float* q_dC = (float*)base;                   // f32, dead after offsample3
  short* q_nC = (short*)(base + SZ * 4);
  short* samp = (short*)(base + SZ * 6);        // dead after k/v gemms
  short* k_nC = (short*)(base + SZ * 8);
  short* v_dN = (short*)(base + SZ * 10);
  short* o_nC = (short*)(base + SZ * 12);
  short* x1t  = (short*)(base + SZ * 14);       // dead after q gemm
  short* Wqb  = (short*)(base + SZ * 16);
  short* Wkb  = Wqb + C_ * C_;
  short* Wvb  = Wkb + C_ * C_;
  short* Wob  = Wvb + C_ * C_;
  // attention partials reuse dead regions:
  short* op0  = samp;               // SZ bf16
  short* op1  = x1t;                // SZ bf16
  float* lp   = q_dC;               // 2*B*H*NS f32 = 786 KB

  dim3 gg(NS_ / 64, C_ / 64, B_);   // (16, 6, 8)

  convw<<<dim3((C_ * C_ + 255) / 256, 4), 256, 0, stream>>>(
      Wq, Wk, Wv, Wo, Wqb, Wkb, Wvb, Wob, C_ * C_);
  transp<<<dim3(NS_ / 32, C_ / 32, B_), 256, 0, stream>>>(x1, x1t);
  gemm_nm<1><<<gg, 256, 0, stream>>>(x1t, Wqb, bq, nullptr, q_nC, q_dC);
  offsample3<<<dim3(B_ * GROUPS_, 64), 256, 0, stream>>>(
      q_dC, x2, off_dw, off_dwb, ln_g, ln_b, off_w, samp);
  gemm_nm<0><<<gg, 256, 0, stream>>>(samp, Wkb, bk, nullptr, k_nC, nullptr);
  gemm_nm<2><<<gg, 256, 0, stream>>>(samp, Wvb, bv, nullptr, v_dN, nullptr);
  attn_split<<<dim3(NS_ / 128, B_ * HEADS_ * 2), 256, 0, stream>>>(
      q_nC, k_nC, v_dN, op0, op1, lp);
  attn_merge<<<dim3(B_ * NS_ * (C_ / 8) / 256), 256, 0, stream>>>(op0, op1, lp, o_nC);
  gemm_nm<3><<<gg, 256, 0, stream>>>(o_nC, Wob, bo, x1, nullptr, (float*)d_out);
}

// Round 5
// 195.292 us; speedup vs baseline: 1.0629x; 1.0629x over previous
//
#include <hip/hip_runtime.h>
#include <math.h>

#define B_  8
#define C_  384
#define NS_ 1024
#define HEADS_ 12
#define HD_ 32
#define GROUPS_ 3
#define CG_ 128
#define EPS_ 1e-5f
// 1/sqrt(32) * log2(e)  (exp computed as exp2)
#define QSC2 (0.17677669529663687f * 1.4426950408889634f)

typedef __attribute__((ext_vector_type(8))) short bf16x8;
typedef __attribute__((ext_vector_type(4))) short bf16x4;
typedef __attribute__((ext_vector_type(4))) float f32x4;
typedef __attribute__((ext_vector_type(8))) __bf16 b8;

static __device__ __forceinline__ short f2b(float f) {
  union { float f; unsigned u; } v; v.f = f;
  unsigned r = v.u + 0x7fffu + ((v.u >> 16) & 1u);   // RNE
  return (short)(r >> 16);
}
static __device__ __forceinline__ float b2f(short s) {
  union { unsigned u; float f; } v; v.u = ((unsigned)(unsigned short)s) << 16;
  return v.f;
}

#if __has_builtin(__builtin_amdgcn_exp2f)
#define EXP2(x) __builtin_amdgcn_exp2f(x)
#else
#define EXP2(x) exp2f(x)
#endif

static __device__ __forceinline__ unsigned cvtpk(float lo, float hi) {
  unsigned r;
  asm("v_cvt_pk_bf16_f32 %0, %1, %2" : "=v"(r) : "v"(lo), "v"(hi));
  return r;
}

static __device__ __forceinline__ f32x4 MFMA(bf16x8 a, bf16x8 b, f32x4 c) {
  return __builtin_amdgcn_mfma_f32_16x16x32_bf16(
      __builtin_bit_cast(b8, a), __builtin_bit_cast(b8, b), c, 0, 0, 0);
}

// ---------------------------------------------------------------------------
// weight fp32 -> bf16 (4 matrices)
// ---------------------------------------------------------------------------
__global__ void convw(const float* __restrict__ s0, const float* __restrict__ s1,
                      const float* __restrict__ s2, const float* __restrict__ s3,
                      short* __restrict__ d0, short* __restrict__ d1,
                      short* __restrict__ d2, short* __restrict__ d3, int n) {
  int i = blockIdx.x * 256 + threadIdx.x;
  if (i >= n) return;
  const float* s = blockIdx.y == 0 ? s0 : blockIdx.y == 1 ? s1 : blockIdx.y == 2 ? s2 : s3;
  short*       d = blockIdx.y == 0 ? d0 : blockIdx.y == 1 ? d1 : blockIdx.y == 2 ? d2 : d3;
  d[i] = f2b(s[i]);
}

// ---------------------------------------------------------------------------
// x1 (B,C,NS) f32 -> x1t (B,NS,C) bf16
// ---------------------------------------------------------------------------
__global__ __launch_bounds__(256) void transp(const float* __restrict__ src,
                                              short* __restrict__ dst) {
  __shared__ float tl[32][33];
  int n0 = blockIdx.x * 32, c0 = blockIdx.y * 32, b = blockIdx.z;
  int tx = threadIdx.x & 31, ty = threadIdx.x >> 5;
#pragma unroll
  for (int i = 0; i < 4; ++i)
    tl[ty + 8 * i][tx] = src[((size_t)b * C_ + c0 + ty + 8 * i) * NS_ + n0 + tx];
  __syncthreads();
#pragma unroll
  for (int i = 0; i < 4; ++i)
    dst[((size_t)b * NS_ + n0 + ty + 8 * i) * C_ + c0 + tx] = f2b(tl[tx][ty + 8 * i]);
}

// ---------------------------------------------------------------------------
// MFMA GEMM, n-major activations (round-3 config: 128x128 tile, 4 waves,
// 64x64/wave, acc 4x4).
// MODE 0: out n-major bf16            (k projection)
// MODE 1: outf d-major f32, outb n-major bf16 * QSC2    (q projection)
// MODE 2: out d-major bf16            (v projection)
// MODE 3: outf d-major f32 + res      (final projection + residual)
// ---------------------------------------------------------------------------
template <int MODE>
__global__ __launch_bounds__(256) void gemm_nm(
    const short* __restrict__ A, const short* __restrict__ Wb,
    const float* __restrict__ bias, const float* __restrict__ res,
    short* __restrict__ outb, float* __restrict__ outf) {
  int b = blockIdx.z;
  int n0 = blockIdx.x * 128;
  int m0 = blockIdx.y * 128;
  int wv = threadIdx.x >> 6;
  int lane = threadIdx.x & 63;
  int g = lane >> 4, r15 = lane & 15;
  int wr = (wv >> 1) * 64, wc = (wv & 1) * 64;

  const short* Ab = A + (size_t)b * NS_ * C_;
  f32x4 acc[4][4];
#pragma unroll
  for (int i = 0; i < 4; ++i)
#pragma unroll
    for (int j = 0; j < 4; ++j) acc[i][j] = (f32x4){0.f, 0.f, 0.f, 0.f};

  for (int kc = 0; kc < C_; kc += 32) {
    bf16x8 af[4], bfr[4];
#pragma unroll
    for (int rt = 0; rt < 4; ++rt)
      af[rt] = *(const bf16x8*)(Ab + (size_t)(n0 + wr + rt * 16 + r15) * C_ + kc + g * 8);
#pragma unroll
    for (int ct = 0; ct < 4; ++ct)
      bfr[ct] = *(const bf16x8*)(Wb + (size_t)(m0 + wc + ct * 16 + r15) * C_ + kc + g * 8);
#pragma unroll
    for (int rt = 0; rt < 4; ++rt)
#pragma unroll
      for (int ct = 0; ct < 4; ++ct) acc[rt][ct] = MFMA(af[rt], bfr[ct], acc[rt][ct]);
  }

#pragma unroll
  for (int rt = 0; rt < 4; ++rt)
#pragma unroll
    for (int ct = 0; ct < 4; ++ct) {
      int m = m0 + wc + ct * 16 + r15;
      int nb = n0 + wr + rt * 16 + g * 4;
      float bv = bias[m];
      f32x4 v = acc[rt][ct];
      v.x += bv; v.y += bv; v.z += bv; v.w += bv;
      if (MODE == 1) {
        *(f32x4*)(outf + ((size_t)b * C_ + m) * NS_ + nb) = v;
        outb[((size_t)b * NS_ + nb + 0) * C_ + m] = f2b(v.x * QSC2);
        outb[((size_t)b * NS_ + nb + 1) * C_ + m] = f2b(v.y * QSC2);
        outb[((size_t)b * NS_ + nb + 2) * C_ + m] = f2b(v.z * QSC2);
        outb[((size_t)b * NS_ + nb + 3) * C_ + m] = f2b(v.w * QSC2);
      } else if (MODE == 0) {
        outb[((size_t)b * NS_ + nb + 0) * C_ + m] = f2b(v.x);
        outb[((size_t)b * NS_ + nb + 1) * C_ + m] = f2b(v.y);
        outb[((size_t)b * NS_ + nb + 2) * C_ + m] = f2b(v.z);
        outb[((size_t)b * NS_ + nb + 3) * C_ + m] = f2b(v.w);
      } else if (MODE == 2) {
        bf16x4 s4 = {f2b(v.x), f2b(v.y), f2b(v.z), f2b(v.w)};
        *(bf16x4*)(outb + ((size_t)b * C_ + m) * NS_ + nb) = s4;
      } else {
        const f32x4 rv = *(const f32x4*)(res + ((size_t)b * C_ + m) * NS_ + nb);
        v.x += rv.x; v.y += rv.y; v.z += rv.z; v.w += rv.w;
        *(f32x4*)(outf + ((size_t)b * C_ + m) * NS_ + nb) = v;
      }
    }
}

// ---------------------------------------------------------------------------
// fused depthwise 5x5 + LN + GELU + offset proj + bilinear sample (unchanged)
// ---------------------------------------------------------------------------
__global__ __launch_bounds__(256) void offsample3(
    const float* __restrict__ qd, const float* __restrict__ x2,
    const float* __restrict__ dw, const float* __restrict__ dwb,
    const float* __restrict__ lng, const float* __restrict__ lnb,
    const float* __restrict__ offw, short* __restrict__ samp) {
  __shared__ float redS[4][16], redSS[4][16], redO0[4][16], redO1[4][16];
  int bg = blockIdx.x, t16 = blockIdx.y;
  int tid = threadIdx.x;
  int cc = tid >> 4, p = tid & 15;
  int wv = tid >> 6, lane = tid & 63;
  int n = t16 * 16 + p;
  int y = t16 >> 1;
  int x = ((t16 & 1) << 4) + p;
  int c0 = cc << 3;

  const float* qb = qd + (size_t)bg * CG_ * NS_;

  float a[8];
  float s = 0.f, ss = 0.f;
#pragma unroll 2
  for (int i = 0; i < 8; ++i) {
    int c = c0 + i;
    const float* qc = qb + (size_t)c * NS_;
    const float* wc = dw + c * 25;
    float acc = dwb[c];
#pragma unroll
    for (int dy = -2; dy <= 2; ++dy) {
      int yy = y + dy;
      if (yy < 0 || yy > 31) continue;
      const float* row = qc + yy * 32;
      const float* wr_ = wc + (dy + 2) * 5;
#pragma unroll
      for (int dx = -2; dx <= 2; ++dx) {
        int xx = x + dx;
        int xcl = min(max(xx, 0), 31);
        float v = row[xcl];
        if (xx != xcl) v = 0.f;
        acc = fmaf(v, wr_[dx + 2], acc);
      }
    }
    a[i] = acc;
    s += acc; ss += acc * acc;
  }

  s  += __shfl_xor(s, 16);  s  += __shfl_xor(s, 32);
  ss += __shfl_xor(ss, 16); ss += __shfl_xor(ss, 32);
  if (lane < 16) { redS[wv][lane] = s; redSS[wv][lane] = ss; }
  __syncthreads();
  float S  = (redS[0][p]  + redS[1][p])  + (redS[2][p]  + redS[3][p]);
  float SS = (redSS[0][p] + redSS[1][p]) + (redSS[2][p] + redSS[3][p]);
  float mu = S * (1.f / CG_);
  float var = SS * (1.f / CG_) - mu * mu;
  float rs = rsqrtf(var + EPS_);

  float o0 = 0.f, o1 = 0.f;
#pragma unroll
  for (int i = 0; i < 8; ++i) {
    int c = c0 + i;
    float z = (a[i] - mu) * rs * lng[c] + lnb[c];
    float u = z * fmaf(0.044715f * z, z, 1.f);
    float e = __expf(-1.5957691216057308f * u);
    float ge = z * __builtin_amdgcn_rcpf(1.f + e);
    o0 = fmaf(offw[c], ge, o0);
    o1 = fmaf(offw[CG_ + c], ge, o1);
  }
  o0 += __shfl_xor(o0, 16); o0 += __shfl_xor(o0, 32);
  o1 += __shfl_xor(o1, 16); o1 += __shfl_xor(o1, 32);
  if (lane < 16) { redO0[wv][lane] = o0; redO1[wv][lane] = o1; }
  __syncthreads();
  float off0 = (redO0[0][p] + redO0[1][p]) + (redO0[2][p] + redO0[3][p]);
  float off1 = (redO1[0][p] + redO1[1][p]) + (redO1[2][p] + redO1[3][p]);

  float gx = (x + 0.5f) * 0.0625f - 1.f;
  float gy = (y + 0.5f) * 0.0625f - 1.f;
  float px = fminf(fmaxf(off0 + gx, -1.f), 1.f);
  float py = fminf(fmaxf(off1 + gy, -1.f), 1.f);
  float ix = (px + 1.f) * 0.5f * 31.f;
  float iy = (py + 1.f) * 0.5f * 31.f;
  float x0f = floorf(ix), y0f = floorf(iy);
  float wx = ix - x0f, wy = iy - y0f;
  int x0 = min(max((int)x0f, 0), 31), x1i = min(x0 + 1, 31);
  int y0 = min(max((int)y0f, 0), 31), y1i = min(y0 + 1, 31);
  int i00 = y0 * 32 + x0,  i01 = y0 * 32 + x1i;
  int i10 = y1i * 32 + x0, i11 = y1i * 32 + x1i;
  float w00 = (1.f - wx) * (1.f - wy), w01 = wx * (1.f - wy);
  float w10 = (1.f - wx) * wy,         w11 = wx * wy;

  int b = bg / GROUPS_, gi = bg % GROUPS_;
  const float* xb = x2 + (size_t)bg * CG_ * NS_;
  short out8[8];
#pragma unroll
  for (int i = 0; i < 8; ++i) {
    const float* xc = xb + (size_t)(c0 + i) * NS_;
    float v = w00 * xc[i00] + w01 * xc[i01] + w10 * xc[i10] + w11 * xc[i11];
    out8[i] = f2b(v);
  }
  *(bf16x8*)(samp + ((size_t)b * NS_ + n) * C_ + gi * CG_ + c0) = *(bf16x8*)out8;
}

// ---------------------------------------------------------------------------
// Split-K MFMA attention, no-max softmax; XCD-locality swizzled flat grid
// (all 8 q-blocks of one (bh,split) task land on the same XCD so K/V stay in
// that XCD's L2), plus explicit 1-chunk-ahead register prefetch (A/B sets).
// ---------------------------------------------------------------------------
__global__ __launch_bounds__(256) void attn_split(
    const short* __restrict__ qn, const short* __restrict__ kn,
    const short* __restrict__ vd, short* __restrict__ op0,
    short* __restrict__ op1, float* __restrict__ lp) {
  // decode bijective swizzle: L = (task%8) + 8*((task/8) + 24*qb)
  int L = blockIdx.x;
  int tq = L >> 3;
  int task = (L & 7) + ((tq % 24) << 3);   // 0..191 = bh*2+s
  int qb = tq / 24;                        // 0..7
  int bh = task >> 1, s = task & 1;
  int b = bh / HEADS_, h = bh % HEADS_;
  int wv = threadIdx.x >> 6, lane = threadIdx.x & 63;
  int g = lane >> 4, q15 = lane & 15;
  int q0 = qb * 128 + wv * 32;

  const short* Qb = qn + (size_t)b * NS_ * C_ + h * HD_;
  const short* Kb = kn + ((size_t)b * NS_ + s * 512) * C_ + h * HD_;
  const short* Vb = vd + ((size_t)b * C_ + h * HD_) * NS_ + s * 512;

  bf16x8 qf[2];
  qf[0] = *(const bf16x8*)(Qb + (size_t)(q0 + q15) * C_ + g * 8);
  qf[1] = *(const bf16x8*)(Qb + (size_t)(q0 + 16 + q15) * C_ + g * 8);

  f32x4 o[2][2];
  o[0][0] = o[0][1] = o[1][0] = o[1][1] = (f32x4){0.f, 0.f, 0.f, 0.f};
  f32x4 lv[2];
  lv[0] = lv[1] = (f32x4){0.f, 0.f, 0.f, 0.f};

#define LOADC(c_, K0, K1, V0, V1)                                              \
  {                                                                            \
    int k0_ = (c_) * 32;                                                       \
    K0 = *(const bf16x8*)(Kb + (size_t)(k0_ + q15) * C_ + g * 8);              \
    K1 = *(const bf16x8*)(Kb + (size_t)(k0_ + 16 + q15) * C_ + g * 8);         \
    const short* vp0_ = Vb + (size_t)(q15) * NS_ + k0_ + g * 4;                \
    const short* vp1_ = Vb + (size_t)(16 + q15) * NS_ + k0_ + g * 4;           \
    bf16x4 a0_ = *(const bf16x4*)(vp0_), b0_ = *(const bf16x4*)(vp0_ + 16);    \
    bf16x4 a1_ = *(const bf16x4*)(vp1_), b1_ = *(const bf16x4*)(vp1_ + 16);    \
    V0 = (bf16x8){a0_.x, a0_.y, a0_.z, a0_.w, b0_.x, b0_.y, b0_.z, b0_.w};     \
    V1 = (bf16x8){a1_.x, a1_.y, a1_.z, a1_.w, b1_.x, b1_.y, b1_.z, b1_.w};     \
  }

#define COMPUTEC(K0, K1, V0, V1)                                               \
  {                                                                            \
    _Pragma("unroll")                                                          \
    for (int qt = 0; qt < 2; ++qt) {                                           \
      f32x4 z_ = {0.f, 0.f, 0.f, 0.f};                                         \
      f32x4 t0 = MFMA(K0, qf[qt], z_);                                         \
      f32x4 t1 = MFMA(K1, qf[qt], z_);                                         \
      f32x4 e0, e1;                                                            \
      e0.x = EXP2(t0.x); e0.y = EXP2(t0.y); e0.z = EXP2(t0.z); e0.w = EXP2(t0.w);\
      e1.x = EXP2(t1.x); e1.y = EXP2(t1.y); e1.z = EXP2(t1.z); e1.w = EXP2(t1.w);\
      lv[qt] += e0; lv[qt] += e1;                                              \
      union { unsigned u[4]; bf16x8 v; } pu;                                   \
      pu.u[0] = cvtpk(e0.x, e0.y);                                             \
      pu.u[1] = cvtpk(e0.z, e0.w);                                             \
      pu.u[2] = cvtpk(e1.x, e1.y);                                             \
      pu.u[3] = cvtpk(e1.z, e1.w);                                             \
      o[qt][0] = MFMA(V0, pu.v, o[qt][0]);                                     \
      o[qt][1] = MFMA(V1, pu.v, o[qt][1]);                                     \
    }                                                                          \
  }

  bf16x8 kA0, kA1, vA0, vA1, kB0, kB1, vB0, vB1;
  LOADC(0, kA0, kA1, vA0, vA1);
#pragma unroll
  for (int cp = 0; cp < 8; ++cp) {
    LOADC(2 * cp + 1, kB0, kB1, vB0, vB1);
    COMPUTEC(kA0, kA1, vA0, vA1);
    if (cp < 7) LOADC(2 * cp + 2, kA0, kA1, vA0, vA1);
    COMPUTEC(kB0, kB1, vB0, vB1);
  }
#undef LOADC
#undef COMPUTEC

  short* opS = s ? op1 : op0;
#pragma unroll
  for (int qt = 0; qt < 2; ++qt) {
    float lt = (lv[qt].x + lv[qt].y) + (lv[qt].z + lv[qt].w);
    lt += __shfl_xor(lt, 16);
    lt += __shfl_xor(lt, 32);
    int q = q0 + qt * 16 + q15;
    if (g == 0) lp[((size_t)(s * B_ + b) * HEADS_ + h) * NS_ + q] = lt;
#pragma unroll
    for (int dt = 0; dt < 2; ++dt) {
      f32x4 ov = o[qt][dt];
      bf16x4 s4 = {f2b(ov.x), f2b(ov.y), f2b(ov.z), f2b(ov.w)};
      *(bf16x4*)(opS + ((size_t)b * NS_ + q) * C_ + h * HD_ + dt * 16 + g * 4) = s4;
    }
  }
}

// ---------------------------------------------------------------------------
// merge: o = (op0 + op1) / (l0 + l1), out n-major bf16
// ---------------------------------------------------------------------------
__global__ __launch_bounds__(256) void attn_merge(
    const short* __restrict__ op0, const short* __restrict__ op1,
    const float* __restrict__ lp, short* __restrict__ on) {
  int idx = blockIdx.x * 256 + threadIdx.x;    // B*NS*48 chunks of 8
  int c8 = idx % (C_ / 8);
  int q  = (idx / (C_ / 8)) % NS_;
  int b  = idx / ((C_ / 8) * NS_);
  int c0 = c8 * 8, h = c0 >> 5;
  size_t off = ((size_t)b * NS_ + q) * C_ + c0;
  bf16x8 a  = *(const bf16x8*)(op0 + off);
  bf16x8 bb = *(const bf16x8*)(op1 + off);
  float l = lp[((size_t)b * HEADS_ + h) * NS_ + q] +
            lp[((size_t)(B_ + b) * HEADS_ + h) * NS_ + q];
  float rl = 1.f / l;
  short r[8];
#pragma unroll
  for (int j = 0; j < 8; ++j) r[j] = f2b((b2f(a[j]) + b2f(bb[j])) * rl);
  *(bf16x8*)(on + off) = *(bf16x8*)r;
}

// ---------------------------------------------------------------------------
extern "C" void kernel_launch(void* const* d_in, const int* in_sizes, int n_in,
                              void* d_out, int out_size, void* d_ws, size_t ws_size,
                              hipStream_t stream) {
  const float* x1      = (const float*)d_in[0];
  const float* x2      = (const float*)d_in[1];
  const float* Wq      = (const float*)d_in[2];
  const float* bq      = (const float*)d_in[3];
  const float* Wk      = (const float*)d_in[4];
  const float* bk      = (const float*)d_in[5];
  const float* Wv      = (const float*)d_in[6];
  const float* bv      = (const float*)d_in[7];
  const float* Wo      = (const float*)d_in[8];
  const float* bo      = (const float*)d_in[9];
  const float* off_dw  = (const float*)d_in[10];
  const float* off_dwb = (const float*)d_in[11];
  const float* ln_g    = (const float*)d_in[12];
  const float* ln_b    = (const float*)d_in[13];
  const float* off_w   = (const float*)d_in[14];

  char* base = (char*)d_ws;
  const size_t SZ = (size_t)B_ * C_ * NS_;
  float* q_dC = (float*)base;                   // f32, dead after offsample3
  short* q_nC = (short*)(base + SZ * 4);
  short* samp = (short*)(base + SZ * 6);        // dead after k/v gemms
  short* k_nC = (short*)(base + SZ * 8);
  short* v_dN = (short*)(base + SZ * 10);
  short* o_nC = (short*)(base + SZ * 12);
  short* x1t  = (short*)(base + SZ * 14);       // dead after q gemm
  short* Wqb  = (short*)(base + SZ * 16);
  short* Wkb  = Wqb + C_ * C_;
  short* Wvb  = Wkb + C_ * C_;
  short* Wob  = Wvb + C_ * C_;
  // attention partials reuse dead regions:
  short* op0  = samp;               // SZ bf16
  short* op1  = x1t;                // SZ bf16
  float* lp   = q_dC;               // 2*B*H*NS f32 = 786 KB

  dim3 gg(NS_ / 128, C_ / 128, B_);   // (8, 3, 8)

  convw<<<dim3((C_ * C_ + 255) / 256, 4), 256, 0, stream>>>(
      Wq, Wk, Wv, Wo, Wqb, Wkb, Wvb, Wob, C_ * C_);
  transp<<<dim3(NS_ / 32, C_ / 32, B_), 256, 0, stream>>>(x1, x1t);
  gemm_nm<1><<<gg, 256, 0, stream>>>(x1t, Wqb, bq, nullptr, q_nC, q_dC);
  offsample3<<<dim3(B_ * GROUPS_, 64), 256, 0, stream>>>(
      q_dC, x2, off_dw, off_dwb, ln_g, ln_b, off_w, samp);
  gemm_nm<0><<<gg, 256, 0, stream>>>(samp, Wkb, bk, nullptr, k_nC, nullptr);
  gemm_nm<2><<<gg, 256, 0, stream>>>(samp, Wvb, bv, nullptr, v_dN, nullptr);
  attn_split<<<dim3(1536), 256, 0, stream>>>(q_nC, k_nC, v_dN, op0, op1, lp);
  attn_merge<<<dim3(B_ * NS_ * (C_ / 8) / 256), 256, 0, stream>>>(op0, op1, lp, o_nC);
  gemm_nm<3><<<gg, 256, 0, stream>>>(o_nC, Wob, bo, x1, nullptr, (float*)d_out);
}

// Round 6
// 162.726 us; speedup vs baseline: 1.2756x; 1.2001x over previous
//
#include <hip/hip_runtime.h>
#include <math.h>

#define B_  8
#define C_  384
#define NS_ 1024
#define HEADS_ 12
#define HD_ 32
#define GROUPS_ 3
#define CG_ 128
#define EPS_ 1e-5f
// 1/sqrt(32) * log2(e)  (exp computed as exp2)
#define QSC2 (0.17677669529663687f * 1.4426950408889634f)

typedef __attribute__((ext_vector_type(8))) short bf16x8;
typedef __attribute__((ext_vector_type(4))) short bf16x4;
typedef __attribute__((ext_vector_type(4))) float f32x4;
typedef __attribute__((ext_vector_type(8))) __bf16 b8;

static __device__ __forceinline__ short f2b(float f) {
  union { float f; unsigned u; } v; v.f = f;
  unsigned r = v.u + 0x7fffu + ((v.u >> 16) & 1u);   // RNE
  return (short)(r >> 16);
}
static __device__ __forceinline__ float b2f(short s) {
  union { unsigned u; float f; } v; v.u = ((unsigned)(unsigned short)s) << 16;
  return v.f;
}

#if __has_builtin(__builtin_amdgcn_exp2f)
#define EXP2(x) __builtin_amdgcn_exp2f(x)
#else
#define EXP2(x) exp2f(x)
#endif

static __device__ __forceinline__ unsigned cvtpk(float lo, float hi) {
  unsigned r;
  asm("v_cvt_pk_bf16_f32 %0, %1, %2" : "=v"(r) : "v"(lo), "v"(hi));
  return r;
}

static __device__ __forceinline__ f32x4 MFMA(bf16x8 a, bf16x8 b, f32x4 c) {
  return __builtin_amdgcn_mfma_f32_16x16x32_bf16(
      __builtin_bit_cast(b8, a), __builtin_bit_cast(b8, b), c, 0, 0, 0);
}

// ---------------------------------------------------------------------------
// weight fp32 -> bf16 (4 matrices)
// ---------------------------------------------------------------------------
__global__ void convw(const float* __restrict__ s0, const float* __restrict__ s1,
                      const float* __restrict__ s2, const float* __restrict__ s3,
                      short* __restrict__ d0, short* __restrict__ d1,
                      short* __restrict__ d2, short* __restrict__ d3, int n) {
  int i = blockIdx.x * 256 + threadIdx.x;
  if (i >= n) return;
  const float* s = blockIdx.y == 0 ? s0 : blockIdx.y == 1 ? s1 : blockIdx.y == 2 ? s2 : s3;
  short*       d = blockIdx.y == 0 ? d0 : blockIdx.y == 1 ? d1 : blockIdx.y == 2 ? d2 : d3;
  d[i] = f2b(s[i]);
}

// ---------------------------------------------------------------------------
// x1 (B,C,NS) f32 -> x1t (B,NS,C) bf16
// ---------------------------------------------------------------------------
__global__ __launch_bounds__(256) void transp(const float* __restrict__ src,
                                              short* __restrict__ dst) {
  __shared__ float tl[32][33];
  int n0 = blockIdx.x * 32, c0 = blockIdx.y * 32, b = blockIdx.z;
  int tx = threadIdx.x & 31, ty = threadIdx.x >> 5;
#pragma unroll
  for (int i = 0; i < 4; ++i)
    tl[ty + 8 * i][tx] = src[((size_t)b * C_ + c0 + ty + 8 * i) * NS_ + n0 + tx];
  __syncthreads();
#pragma unroll
  for (int i = 0; i < 4; ++i)
    dst[((size_t)b * NS_ + n0 + ty + 8 * i) * C_ + c0 + tx] = f2b(tl[tx][ty + 8 * i]);
}

// ---------------------------------------------------------------------------
// MFMA GEMM, n-major activations (128x128 tile, 4 waves, 64x64/wave, acc 4x4)
// MODE 0: out n-major bf16            (k projection)
// MODE 1: outf d-major f32, outb n-major bf16 * QSC2    (q projection)
// MODE 2: out d-major bf16            (v projection)
// MODE 3: outf d-major f32 + res      (final projection + residual)
// ---------------------------------------------------------------------------
template <int MODE>
__global__ __launch_bounds__(256) void gemm_nm(
    const short* __restrict__ A, const short* __restrict__ Wb,
    const float* __restrict__ bias, const float* __restrict__ res,
    short* __restrict__ outb, float* __restrict__ outf) {
  int b = blockIdx.z;
  int n0 = blockIdx.x * 128;
  int m0 = blockIdx.y * 128;
  int wv = threadIdx.x >> 6;
  int lane = threadIdx.x & 63;
  int g = lane >> 4, r15 = lane & 15;
  int wr = (wv >> 1) * 64, wc = (wv & 1) * 64;

  const short* Ab = A + (size_t)b * NS_ * C_;
  f32x4 acc[4][4];
#pragma unroll
  for (int i = 0; i < 4; ++i)
#pragma unroll
    for (int j = 0; j < 4; ++j) acc[i][j] = (f32x4){0.f, 0.f, 0.f, 0.f};

  for (int kc = 0; kc < C_; kc += 32) {
    bf16x8 af[4], bfr[4];
#pragma unroll
    for (int rt = 0; rt < 4; ++rt)
      af[rt] = *(const bf16x8*)(Ab + (size_t)(n0 + wr + rt * 16 + r15) * C_ + kc + g * 8);
#pragma unroll
    for (int ct = 0; ct < 4; ++ct)
      bfr[ct] = *(const bf16x8*)(Wb + (size_t)(m0 + wc + ct * 16 + r15) * C_ + kc + g * 8);
#pragma unroll
    for (int rt = 0; rt < 4; ++rt)
#pragma unroll
      for (int ct = 0; ct < 4; ++ct) acc[rt][ct] = MFMA(af[rt], bfr[ct], acc[rt][ct]);
  }

#pragma unroll
  for (int rt = 0; rt < 4; ++rt)
#pragma unroll
    for (int ct = 0; ct < 4; ++ct) {
      int m = m0 + wc + ct * 16 + r15;
      int nb = n0 + wr + rt * 16 + g * 4;
      float bv = bias[m];
      f32x4 v = acc[rt][ct];
      v.x += bv; v.y += bv; v.z += bv; v.w += bv;
      if (MODE == 1) {
        *(f32x4*)(outf + ((size_t)b * C_ + m) * NS_ + nb) = v;
        outb[((size_t)b * NS_ + nb + 0) * C_ + m] = f2b(v.x * QSC2);
        outb[((size_t)b * NS_ + nb + 1) * C_ + m] = f2b(v.y * QSC2);
        outb[((size_t)b * NS_ + nb + 2) * C_ + m] = f2b(v.z * QSC2);
        outb[((size_t)b * NS_ + nb + 3) * C_ + m] = f2b(v.w * QSC2);
      } else if (MODE == 0) {
        outb[((size_t)b * NS_ + nb + 0) * C_ + m] = f2b(v.x);
        outb[((size_t)b * NS_ + nb + 1) * C_ + m] = f2b(v.y);
        outb[((size_t)b * NS_ + nb + 2) * C_ + m] = f2b(v.z);
        outb[((size_t)b * NS_ + nb + 3) * C_ + m] = f2b(v.w);
      } else if (MODE == 2) {
        bf16x4 s4 = {f2b(v.x), f2b(v.y), f2b(v.z), f2b(v.w)};
        *(bf16x4*)(outb + ((size_t)b * C_ + m) * NS_ + nb) = s4;
      } else {
        const f32x4 rv = *(const f32x4*)(res + ((size_t)b * C_ + m) * NS_ + nb);
        v.x += rv.x; v.y += rv.y; v.z += rv.z; v.w += rv.w;
        *(f32x4*)(outf + ((size_t)b * C_ + m) * NS_ + nb) = v;
      }
    }
}

// ---------------------------------------------------------------------------
// fused depthwise 5x5 + LN + GELU + offset proj + bilinear sample.
// Full unroll over the 8 channels -> 8 independent load chains (ILP).
// ---------------------------------------------------------------------------
__global__ __launch_bounds__(256) void offsample3(
    const float* __restrict__ qd, const float* __restrict__ x2,
    const float* __restrict__ dw, const float* __restrict__ dwb,
    const float* __restrict__ lng, const float* __restrict__ lnb,
    const float* __restrict__ offw, short* __restrict__ samp) {
  __shared__ float redS[4][16], redSS[4][16], redO0[4][16], redO1[4][16];
  int bg = blockIdx.x, t16 = blockIdx.y;
  int tid = threadIdx.x;
  int cc = tid >> 4, p = tid & 15;
  int wv = tid >> 6, lane = tid & 63;
  int n = t16 * 16 + p;
  int y = t16 >> 1;
  int x = ((t16 & 1) << 4) + p;
  int c0 = cc << 3;

  const float* qb = qd + (size_t)bg * CG_ * NS_;

  float a[8];
  float s = 0.f, ss = 0.f;
#pragma unroll
  for (int i = 0; i < 8; ++i) {
    int c = c0 + i;
    const float* qc = qb + (size_t)c * NS_;
    const float* wc = dw + c * 25;
    float acc = dwb[c];
#pragma unroll
    for (int dy = -2; dy <= 2; ++dy) {
      int yy = y + dy;
      if (yy < 0 || yy > 31) continue;
      const float* row = qc + yy * 32;
      const float* wr_ = wc + (dy + 2) * 5;
#pragma unroll
      for (int dx = -2; dx <= 2; ++dx) {
        int xx = x + dx;
        int xcl = min(max(xx, 0), 31);
        float v = row[xcl];
        if (xx != xcl) v = 0.f;
        acc = fmaf(v, wr_[dx + 2], acc);
      }
    }
    a[i] = acc;
    s += acc; ss += acc * acc;
  }

  s  += __shfl_xor(s, 16);  s  += __shfl_xor(s, 32);
  ss += __shfl_xor(ss, 16); ss += __shfl_xor(ss, 32);
  if (lane < 16) { redS[wv][lane] = s; redSS[wv][lane] = ss; }
  __syncthreads();
  float S  = (redS[0][p]  + redS[1][p])  + (redS[2][p]  + redS[3][p]);
  float SS = (redSS[0][p] + redSS[1][p]) + (redSS[2][p] + redSS[3][p]);
  float mu = S * (1.f / CG_);
  float var = SS * (1.f / CG_) - mu * mu;
  float rs = rsqrtf(var + EPS_);

  float o0 = 0.f, o1 = 0.f;
#pragma unroll
  for (int i = 0; i < 8; ++i) {
    int c = c0 + i;
    float z = (a[i] - mu) * rs * lng[c] + lnb[c];
    float u = z * fmaf(0.044715f * z, z, 1.f);
    float e = __expf(-1.5957691216057308f * u);
    float ge = z * __builtin_amdgcn_rcpf(1.f + e);
    o0 = fmaf(offw[c], ge, o0);
    o1 = fmaf(offw[CG_ + c], ge, o1);
  }
  o0 += __shfl_xor(o0, 16); o0 += __shfl_xor(o0, 32);
  o1 += __shfl_xor(o1, 16); o1 += __shfl_xor(o1, 32);
  if (lane < 16) { redO0[wv][lane] = o0; redO1[wv][lane] = o1; }
  __syncthreads();
  float off0 = (redO0[0][p] + redO0[1][p]) + (redO0[2][p] + redO0[3][p]);
  float off1 = (redO1[0][p] + redO1[1][p]) + (redO1[2][p] + redO1[3][p]);

  float gx = (x + 0.5f) * 0.0625f - 1.f;
  float gy = (y + 0.5f) * 0.0625f - 1.f;
  float px = fminf(fmaxf(off0 + gx, -1.f), 1.f);
  float py = fminf(fmaxf(off1 + gy, -1.f), 1.f);
  float ix = (px + 1.f) * 0.5f * 31.f;
  float iy = (py + 1.f) * 0.5f * 31.f;
  float x0f = floorf(ix), y0f = floorf(iy);
  float wx = ix - x0f, wy = iy - y0f;
  int x0 = min(max((int)x0f, 0), 31), x1i = min(x0 + 1, 31);
  int y0 = min(max((int)y0f, 0), 31), y1i = min(y0 + 1, 31);
  int i00 = y0 * 32 + x0,  i01 = y0 * 32 + x1i;
  int i10 = y1i * 32 + x0, i11 = y1i * 32 + x1i;
  float w00 = (1.f - wx) * (1.f - wy), w01 = wx * (1.f - wy);
  float w10 = (1.f - wx) * wy,         w11 = wx * wy;

  int b = bg / GROUPS_, gi = bg % GROUPS_;
  const float* xb = x2 + (size_t)bg * CG_ * NS_;
  short out8[8];
#pragma unroll
  for (int i = 0; i < 8; ++i) {
    const float* xc = xb + (size_t)(c0 + i) * NS_;
    float v = w00 * xc[i00] + w01 * xc[i01] + w10 * xc[i10] + w11 * xc[i11];
    out8[i] = f2b(v);
  }
  *(bf16x8*)(samp + ((size_t)b * NS_ + n) * C_ + gi * CG_ + c0) = *(bf16x8*)out8;
}

// ---------------------------------------------------------------------------
// Split-K MFMA attention, 64 queries/wave (4 Q-frags per K/V load set -> 4x
// arithmetic intensity vs r5). No-max softmax; XCD-locality swizzled grid;
// 1-deep A/B register prefetch.
// ---------------------------------------------------------------------------
__global__ __launch_bounds__(256) void attn_split(
    const short* __restrict__ qn, const short* __restrict__ kn,
    const short* __restrict__ vd, short* __restrict__ op0,
    short* __restrict__ op1, float* __restrict__ lp) {
  // grid = 768; L = (task%8) + 8*((task/8) + 24*qblk); task=bh*2+s, qblk 0..3
  int L = blockIdx.x;
  int tq = L >> 3;
  int task = (L & 7) + ((tq % 24) << 3);   // 0..191
  int qblk = tq / 24;                      // 0..3
  int bh = task >> 1, s = task & 1;
  int b = bh / HEADS_, h = bh % HEADS_;
  int wv = threadIdx.x >> 6, lane = threadIdx.x & 63;
  int g = lane >> 4, q15 = lane & 15;
  int q0 = qblk * 256 + wv * 64;

  const short* Qb = qn + (size_t)b * NS_ * C_ + h * HD_;
  const short* Kb = kn + ((size_t)b * NS_ + s * 512) * C_ + h * HD_;
  const short* Vb = vd + ((size_t)b * C_ + h * HD_) * NS_ + s * 512;

  bf16x8 qf[4];
#pragma unroll
  for (int qt = 0; qt < 4; ++qt)
    qf[qt] = *(const bf16x8*)(Qb + (size_t)(q0 + qt * 16 + q15) * C_ + g * 8);

  f32x4 o[4][2];
#pragma unroll
  for (int qt = 0; qt < 4; ++qt) o[qt][0] = o[qt][1] = (f32x4){0.f, 0.f, 0.f, 0.f};
  float l[4] = {0.f, 0.f, 0.f, 0.f};

#define LOADC(c_, K0, K1, V0, V1)                                              \
  {                                                                            \
    int k0_ = (c_) * 32;                                                       \
    K0 = *(const bf16x8*)(Kb + (size_t)(k0_ + q15) * C_ + g * 8);              \
    K1 = *(const bf16x8*)(Kb + (size_t)(k0_ + 16 + q15) * C_ + g * 8);         \
    const short* vp0_ = Vb + (size_t)(q15) * NS_ + k0_ + g * 4;                \
    const short* vp1_ = Vb + (size_t)(16 + q15) * NS_ + k0_ + g * 4;           \
    bf16x4 a0_ = *(const bf16x4*)(vp0_), b0_ = *(const bf16x4*)(vp0_ + 16);    \
    bf16x4 a1_ = *(const bf16x4*)(vp1_), b1_ = *(const bf16x4*)(vp1_ + 16);    \
    V0 = (bf16x8){a0_.x, a0_.y, a0_.z, a0_.w, b0_.x, b0_.y, b0_.z, b0_.w};     \
    V1 = (bf16x8){a1_.x, a1_.y, a1_.z, a1_.w, b1_.x, b1_.y, b1_.z, b1_.w};     \
  }

#define COMPUTEC(K0, K1, V0, V1)                                               \
  {                                                                            \
    _Pragma("unroll")                                                          \
    for (int qt = 0; qt < 4; ++qt) {                                           \
      f32x4 z_ = {0.f, 0.f, 0.f, 0.f};                                         \
      f32x4 t0 = MFMA(K0, qf[qt], z_);                                         \
      f32x4 t1 = MFMA(K1, qf[qt], z_);                                         \
      f32x4 e0, e1;                                                            \
      e0.x = EXP2(t0.x); e0.y = EXP2(t0.y); e0.z = EXP2(t0.z); e0.w = EXP2(t0.w);\
      e1.x = EXP2(t1.x); e1.y = EXP2(t1.y); e1.z = EXP2(t1.z); e1.w = EXP2(t1.w);\
      l[qt] += ((e0.x + e0.y) + (e0.z + e0.w)) + ((e1.x + e1.y) + (e1.z + e1.w));\
      union { unsigned u[4]; bf16x8 v; } pu;                                   \
      pu.u[0] = cvtpk(e0.x, e0.y);                                             \
      pu.u[1] = cvtpk(e0.z, e0.w);                                             \
      pu.u[2] = cvtpk(e1.x, e1.y);                                             \
      pu.u[3] = cvtpk(e1.z, e1.w);                                             \
      o[qt][0] = MFMA(V0, pu.v, o[qt][0]);                                     \
      o[qt][1] = MFMA(V1, pu.v, o[qt][1]);                                     \
    }                                                                          \
  }

  bf16x8 kA0, kA1, vA0, vA1, kB0, kB1, vB0, vB1;
  LOADC(0, kA0, kA1, vA0, vA1);
#pragma unroll
  for (int cp = 0; cp < 8; ++cp) {
    LOADC(2 * cp + 1, kB0, kB1, vB0, vB1);
    COMPUTEC(kA0, kA1, vA0, vA1);
    if (cp < 7) LOADC(2 * cp + 2, kA0, kA1, vA0, vA1);
    COMPUTEC(kB0, kB1, vB0, vB1);
  }
#undef LOADC
#undef COMPUTEC

  short* opS = s ? op1 : op0;
#pragma unroll
  for (int qt = 0; qt < 4; ++qt) {
    float lt = l[qt];
    lt += __shfl_xor(lt, 16);
    lt += __shfl_xor(lt, 32);
    int q = q0 + qt * 16 + q15;
    if (g == 0) lp[((size_t)(s * B_ + b) * HEADS_ + h) * NS_ + q] = lt;
#pragma unroll
    for (int dt = 0; dt < 2; ++dt) {
      f32x4 ov = o[qt][dt];
      bf16x4 s4 = {f2b(ov.x), f2b(ov.y), f2b(ov.z), f2b(ov.w)};
      *(bf16x4*)(opS + ((size_t)b * NS_ + q) * C_ + h * HD_ + dt * 16 + g * 4) = s4;
    }
  }
}

// ---------------------------------------------------------------------------
// merge: o = (op0 + op1) / (l0 + l1), out n-major bf16
// ---------------------------------------------------------------------------
__global__ __launch_bounds__(256) void attn_merge(
    const short* __restrict__ op0, const short* __restrict__ op1,
    const float* __restrict__ lp, short* __restrict__ on) {
  int idx = blockIdx.x * 256 + threadIdx.x;
  int c8 = idx % (C_ / 8);
  int q  = (idx / (C_ / 8)) % NS_;
  int b  = idx / ((C_ / 8) * NS_);
  int c0 = c8 * 8, h = c0 >> 5;
  size_t off = ((size_t)b * NS_ + q) * C_ + c0;
  bf16x8 a  = *(const bf16x8*)(op0 + off);
  bf16x8 bb = *(const bf16x8*)(op1 + off);
  float l = lp[((size_t)b * HEADS_ + h) * NS_ + q] +
            lp[((size_t)(B_ + b) * HEADS_ + h) * NS_ + q];
  float rl = 1.f / l;
  short r[8];
#pragma unroll
  for (int j = 0; j < 8; ++j) r[j] = f2b((b2f(a[j]) + b2f(bb[j])) * rl);
  *(bf16x8*)(on + off) = *(bf16x8*)r;
}

// ---------------------------------------------------------------------------
extern "C" void kernel_launch(void* const* d_in, const int* in_sizes, int n_in,
                              void* d_out, int out_size, void* d_ws, size_t ws_size,
                              hipStream_t stream) {
  const float* x1      = (const float*)d_in[0];
  const float* x2      = (const float*)d_in[1];
  const float* Wq      = (const float*)d_in[2];
  const float* bq      = (const float*)d_in[3];
  const float* Wk      = (const float*)d_in[4];
  const float* bk      = (const float*)d_in[5];
  const float* Wv      = (const float*)d_in[6];
  const float* bv      = (const float*)d_in[7];
  const float* Wo      = (const float*)d_in[8];
  const float* bo      = (const float*)d_in[9];
  const float* off_dw  = (const float*)d_in[10];
  const float* off_dwb = (const float*)d_in[11];
  const float* ln_g    = (const float*)d_in[12];
  const float* ln_b    = (const float*)d_in[13];
  const float* off_w   = (const float*)d_in[14];

  char* base = (char*)d_ws;
  const size_t SZ = (size_t)B_ * C_ * NS_;
  float* q_dC = (float*)base;                   // f32, dead after offsample3
  short* q_nC = (short*)(base + SZ * 4);
  short* samp = (short*)(base + SZ * 6);        // dead after k/v gemms
  short* k_nC = (short*)(base + SZ * 8);
  short* v_dN = (short*)(base + SZ * 10);
  short* o_nC = (short*)(base + SZ * 12);
  short* x1t  = (short*)(base + SZ * 14);       // dead after q gemm
  short* Wqb  = (short*)(base + SZ * 16);
  short* Wkb  = Wqb + C_ * C_;
  short* Wvb  = Wkb + C_ * C_;
  short* Wob  = Wvb + C_ * C_;
  // attention partials reuse dead regions:
  short* op0  = samp;               // SZ bf16
  short* op1  = x1t;                // SZ bf16
  float* lp   = q_dC;               // 2*B*H*NS f32 = 786 KB

  dim3 gg(NS_ / 128, C_ / 128, B_);   // (8, 3, 8)

  convw<<<dim3((C_ * C_ + 255) / 256, 4), 256, 0, stream>>>(
      Wq, Wk, Wv, Wo, Wqb, Wkb, Wvb, Wob, C_ * C_);
  transp<<<dim3(NS_ / 32, C_ / 32, B_), 256, 0, stream>>>(x1, x1t);
  gemm_nm<1><<<gg, 256, 0, stream>>>(x1t, Wqb, bq, nullptr, q_nC, q_dC);
  offsample3<<<dim3(B_ * GROUPS_, 64), 256, 0, stream>>>(
      q_dC, x2, off_dw, off_dwb, ln_g, ln_b, off_w, samp);
  gemm_nm<0><<<gg, 256, 0, stream>>>(samp, Wkb, bk, nullptr, k_nC, nullptr);
  gemm_nm<2><<<gg, 256, 0, stream>>>(samp, Wvb, bv, nullptr, v_dN, nullptr);
  attn_split<<<dim3(768), 256, 0, stream>>>(q_nC, k_nC, v_dN, op0, op1, lp);
  attn_merge<<<dim3(B_ * NS_ * (C_ / 8) / 256), 256, 0, stream>>>(op0, op1, lp, o_nC);
  gemm_nm<3><<<gg, 256, 0, stream>>>(o_nC, Wob, bo, x1, nullptr, (float*)d_out);
}

// Round 7
// 161.864 us; speedup vs baseline: 1.2824x; 1.0053x over previous
//
#include <hip/hip_runtime.h>
#include <math.h>

#define B_  8
#define C_  384
#define NS_ 1024
#define HEADS_ 12
#define HD_ 32
#define GROUPS_ 3
#define CG_ 128
#define EPS_ 1e-5f
// 1/sqrt(32) * log2(e)  (exp computed as exp2)
#define QSC2 (0.17677669529663687f * 1.4426950408889634f)

typedef __attribute__((ext_vector_type(8))) short bf16x8;
typedef __attribute__((ext_vector_type(4))) short bf16x4;
typedef __attribute__((ext_vector_type(4))) float f32x4;
typedef __attribute__((ext_vector_type(8))) __bf16 b8;

static __device__ __forceinline__ short f2b(float f) {
  union { float f; unsigned u; } v; v.f = f;
  unsigned r = v.u + 0x7fffu + ((v.u >> 16) & 1u);   // RNE
  return (short)(r >> 16);
}
static __device__ __forceinline__ float b2f(short s) {
  union { unsigned u; float f; } v; v.u = ((unsigned)(unsigned short)s) << 16;
  return v.f;
}

#if __has_builtin(__builtin_amdgcn_exp2f)
#define EXP2(x) __builtin_amdgcn_exp2f(x)
#else
#define EXP2(x) exp2f(x)
#endif

static __device__ __forceinline__ unsigned cvtpk(float lo, float hi) {
  unsigned r;
  asm("v_cvt_pk_bf16_f32 %0, %1, %2" : "=v"(r) : "v"(lo), "v"(hi));
  return r;
}

static __device__ __forceinline__ f32x4 MFMA(bf16x8 a, bf16x8 b, f32x4 c) {
  return __builtin_amdgcn_mfma_f32_16x16x32_bf16(
      __builtin_bit_cast(b8, a), __builtin_bit_cast(b8, b), c, 0, 0, 0);
}

// ---------------------------------------------------------------------------
// weight fp32 -> bf16 (4 matrices)
// ---------------------------------------------------------------------------
__global__ void convw(const float* __restrict__ s0, const float* __restrict__ s1,
                      const float* __restrict__ s2, const float* __restrict__ s3,
                      short* __restrict__ d0, short* __restrict__ d1,
                      short* __restrict__ d2, short* __restrict__ d3, int n) {
  int i = blockIdx.x * 256 + threadIdx.x;
  if (i >= n) return;
  const float* s = blockIdx.y == 0 ? s0 : blockIdx.y == 1 ? s1 : blockIdx.y == 2 ? s2 : s3;
  short*       d = blockIdx.y == 0 ? d0 : blockIdx.y == 1 ? d1 : blockIdx.y == 2 ? d2 : d3;
  d[i] = f2b(s[i]);
}

// ---------------------------------------------------------------------------
// x1 (B,C,NS) f32 -> x1t (B,NS,C) bf16
// ---------------------------------------------------------------------------
__global__ __launch_bounds__(256) void transp(const float* __restrict__ src,
                                              short* __restrict__ dst) {
  __shared__ float tl[32][33];
  int n0 = blockIdx.x * 32, c0 = blockIdx.y * 32, b = blockIdx.z;
  int tx = threadIdx.x & 31, ty = threadIdx.x >> 5;
#pragma unroll
  for (int i = 0; i < 4; ++i)
    tl[ty + 8 * i][tx] = src[((size_t)b * C_ + c0 + ty + 8 * i) * NS_ + n0 + tx];
  __syncthreads();
#pragma unroll
  for (int i = 0; i < 4; ++i)
    dst[((size_t)b * NS_ + n0 + ty + 8 * i) * C_ + c0 + tx] = f2b(tl[tx][ty + 8 * i]);
}

// ---------------------------------------------------------------------------
// MFMA GEMM, n-major activations (128x128 tile, 4 waves, 64x64/wave, acc 4x4)
// MODE 0: out n-major bf16            (k projection)
// MODE 1: outf d-major f32, outb n-major bf16 * QSC2    (q projection)
// MODE 2: out d-major bf16            (v projection)
// MODE 3: outf d-major f32 + res      (final projection + residual)
// ---------------------------------------------------------------------------
template <int MODE>
__global__ __launch_bounds__(256) void gemm_nm(
    const short* __restrict__ A, const short* __restrict__ Wb,
    const float* __restrict__ bias, const float* __restrict__ res,
    short* __restrict__ outb, float* __restrict__ outf) {
  int b = blockIdx.z;
  int n0 = blockIdx.x * 128;
  int m0 = blockIdx.y * 128;
  int wv = threadIdx.x >> 6;
  int lane = threadIdx.x & 63;
  int g = lane >> 4, r15 = lane & 15;
  int wr = (wv >> 1) * 64, wc = (wv & 1) * 64;

  const short* Ab = A + (size_t)b * NS_ * C_;
  f32x4 acc[4][4];
#pragma unroll
  for (int i = 0; i < 4; ++i)
#pragma unroll
    for (int j = 0; j < 4; ++j) acc[i][j] = (f32x4){0.f, 0.f, 0.f, 0.f};

  for (int kc = 0; kc < C_; kc += 32) {
    bf16x8 af[4], bfr[4];
#pragma unroll
    for (int rt = 0; rt < 4; ++rt)
      af[rt] = *(const bf16x8*)(Ab + (size_t)(n0 + wr + rt * 16 + r15) * C_ + kc + g * 8);
#pragma unroll
    for (int ct = 0; ct < 4; ++ct)
      bfr[ct] = *(const bf16x8*)(Wb + (size_t)(m0 + wc + ct * 16 + r15) * C_ + kc + g * 8);
#pragma unroll
    for (int rt = 0; rt < 4; ++rt)
#pragma unroll
      for (int ct = 0; ct < 4; ++ct) acc[rt][ct] = MFMA(af[rt], bfr[ct], acc[rt][ct]);
  }

#pragma unroll
  for (int rt = 0; rt < 4; ++rt)
#pragma unroll
    for (int ct = 0; ct < 4; ++ct) {
      int m = m0 + wc + ct * 16 + r15;
      int nb = n0 + wr + rt * 16 + g * 4;
      float bv = bias[m];
      f32x4 v = acc[rt][ct];
      v.x += bv; v.y += bv; v.z += bv; v.w += bv;
      if (MODE == 1) {
        *(f32x4*)(outf + ((size_t)b * C_ + m) * NS_ + nb) = v;
        outb[((size_t)b * NS_ + nb + 0) * C_ + m] = f2b(v.x * QSC2);
        outb[((size_t)b * NS_ + nb + 1) * C_ + m] = f2b(v.y * QSC2);
        outb[((size_t)b * NS_ + nb + 2) * C_ + m] = f2b(v.z * QSC2);
        outb[((size_t)b * NS_ + nb + 3) * C_ + m] = f2b(v.w * QSC2);
      } else if (MODE == 0) {
        outb[((size_t)b * NS_ + nb + 0) * C_ + m] = f2b(v.x);
        outb[((size_t)b * NS_ + nb + 1) * C_ + m] = f2b(v.y);
        outb[((size_t)b * NS_ + nb + 2) * C_ + m] = f2b(v.z);
        outb[((size_t)b * NS_ + nb + 3) * C_ + m] = f2b(v.w);
      } else if (MODE == 2) {
        bf16x4 s4 = {f2b(v.x), f2b(v.y), f2b(v.z), f2b(v.w)};
        *(bf16x4*)(outb + ((size_t)b * C_ + m) * NS_ + nb) = s4;
      } else {
        const f32x4 rv = *(const f32x4*)(res + ((size_t)b * C_ + m) * NS_ + nb);
        v.x += rv.x; v.y += rv.y; v.z += rv.z; v.w += rv.w;
        *(f32x4*)(outf + ((size_t)b * C_ + m) * NS_ + nb) = v;
      }
    }
}

// ---------------------------------------------------------------------------
// fused depthwise 5x5 + LN + GELU + offset proj + bilinear sample.
// Full unroll over the 8 channels -> 8 independent load chains (ILP).
// ---------------------------------------------------------------------------
__global__ __launch_bounds__(256) void offsample3(
    const float* __restrict__ qd, const float* __restrict__ x2,
    const float* __restrict__ dw, const float* __restrict__ dwb,
    const float* __restrict__ lng, const float* __restrict__ lnb,
    const float* __restrict__ offw, short* __restrict__ samp) {
  __shared__ float redS[4][16], redSS[4][16], redO0[4][16], redO1[4][16];
  int bg = blockIdx.x, t16 = blockIdx.y;
  int tid = threadIdx.x;
  int cc = tid >> 4, p = tid & 15;
  int wv = tid >> 6, lane = tid & 63;
  int n = t16 * 16 + p;
  int y = t16 >> 1;
  int x = ((t16 & 1) << 4) + p;
  int c0 = cc << 3;

  const float* qb = qd + (size_t)bg * CG_ * NS_;

  float a[8];
  float s = 0.f, ss = 0.f;
#pragma unroll
  for (int i = 0; i < 8; ++i) {
    int c = c0 + i;
    const float* qc = qb + (size_t)c * NS_;
    const float* wc = dw + c * 25;
    float acc = dwb[c];
#pragma unroll
    for (int dy = -2; dy <= 2; ++dy) {
      int yy = y + dy;
      if (yy < 0 || yy > 31) continue;
      const float* row = qc + yy * 32;
      const float* wr_ = wc + (dy + 2) * 5;
#pragma unroll
      for (int dx = -2; dx <= 2; ++dx) {
        int xx = x + dx;
        int xcl = min(max(xx, 0), 31);
        float v = row[xcl];
        if (xx != xcl) v = 0.f;
        acc = fmaf(v, wr_[dx + 2], acc);
      }
    }
    a[i] = acc;
    s += acc; ss += acc * acc;
  }

  s  += __shfl_xor(s, 16);  s  += __shfl_xor(s, 32);
  ss += __shfl_xor(ss, 16); ss += __shfl_xor(ss, 32);
  if (lane < 16) { redS[wv][lane] = s; redSS[wv][lane] = ss; }
  __syncthreads();
  float S  = (redS[0][p]  + redS[1][p])  + (redS[2][p]  + redS[3][p]);
  float SS = (redSS[0][p] + redSS[1][p]) + (redSS[2][p] + redSS[3][p]);
  float mu = S * (1.f / CG_);
  float var = SS * (1.f / CG_) - mu * mu;
  float rs = rsqrtf(var + EPS_);

  float o0 = 0.f, o1 = 0.f;
#pragma unroll
  for (int i = 0; i < 8; ++i) {
    int c = c0 + i;
    float z = (a[i] - mu) * rs * lng[c] + lnb[c];
    float u = z * fmaf(0.044715f * z, z, 1.f);
    float e = __expf(-1.5957691216057308f * u);
    float ge = z * __builtin_amdgcn_rcpf(1.f + e);
    o0 = fmaf(offw[c], ge, o0);
    o1 = fmaf(offw[CG_ + c], ge, o1);
  }
  o0 += __shfl_xor(o0, 16); o0 += __shfl_xor(o0, 32);
  o1 += __shfl_xor(o1, 16); o1 += __shfl_xor(o1, 32);
  if (lane < 16) { redO0[wv][lane] = o0; redO1[wv][lane] = o1; }
  __syncthreads();
  float off0 = (redO0[0][p] + redO0[1][p]) + (redO0[2][p] + redO0[3][p]);
  float off1 = (redO1[0][p] + redO1[1][p]) + (redO1[2][p] + redO1[3][p]);

  float gx = (x + 0.5f) * 0.0625f - 1.f;
  float gy = (y + 0.5f) * 0.0625f - 1.f;
  float px = fminf(fmaxf(off0 + gx, -1.f), 1.f);
  float py = fminf(fmaxf(off1 + gy, -1.f), 1.f);
  float ix = (px + 1.f) * 0.5f * 31.f;
  float iy = (py + 1.f) * 0.5f * 31.f;
  float x0f = floorf(ix), y0f = floorf(iy);
  float wx = ix - x0f, wy = iy - y0f;
  int x0 = min(max((int)x0f, 0), 31), x1i = min(x0 + 1, 31);
  int y0 = min(max((int)y0f, 0), 31), y1i = min(y0 + 1, 31);
  int i00 = y0 * 32 + x0,  i01 = y0 * 32 + x1i;
  int i10 = y1i * 32 + x0, i11 = y1i * 32 + x1i;
  float w00 = (1.f - wx) * (1.f - wy), w01 = wx * (1.f - wy);
  float w10 = (1.f - wx) * wy,         w11 = wx * wy;

  int b = bg / GROUPS_, gi = bg % GROUPS_;
  const float* xb = x2 + (size_t)bg * CG_ * NS_;
  short out8[8];
#pragma unroll
  for (int i = 0; i < 8; ++i) {
    const float* xc = xb + (size_t)(c0 + i) * NS_;
    float v = w00 * xc[i00] + w01 * xc[i01] + w10 * xc[i10] + w11 * xc[i11];
    out8[i] = f2b(v);
  }
  *(bf16x8*)(samp + ((size_t)b * NS_ + n) * C_ + gi * CG_ + c0) = *(bf16x8*)out8;
}

// ---------------------------------------------------------------------------
// Split-K MFMA attention, 64 queries/wave (4 Q-frags per K/V load set -> 4x
// arithmetic intensity vs r5). No-max softmax; XCD-locality swizzled grid;
// 1-deep A/B register prefetch.
// ---------------------------------------------------------------------------
__global__ __launch_bounds__(256) void attn_split(
    const short* __restrict__ qn, const short* __restrict__ kn,
    const short* __restrict__ vd, short* __restrict__ op0,
    short* __restrict__ op1, float* __restrict__ lp) {
  // grid = 768; L = (task%8) + 8*((task/8) + 24*qblk); task=bh*2+s, qblk 0..3
  int L = blockIdx.x;
  int tq = L >> 3;
  int task = (L & 7) + ((tq % 24) << 3);   // 0..191
  int qblk = tq / 24;                      // 0..3
  int bh = task >> 1, s = task & 1;
  int b = bh / HEADS_, h = bh % HEADS_;
  int wv = threadIdx.x >> 6, lane = threadIdx.x & 63;
  int g = lane >> 4, q15 = lane & 15;
  int q0 = qblk * 256 + wv * 64;

  const short* Qb = qn + (size_t)b * NS_ * C_ + h * HD_;
  const short* Kb = kn + ((size_t)b * NS_ + s * 512) * C_ + h * HD_;
  const short* Vb = vd + ((size_t)b * C_ + h * HD_) * NS_ + s * 512;

  bf16x8 qf[4];
#pragma unroll
  for (int qt = 0; qt < 4; ++qt)
    qf[qt] = *(const bf16x8*)(Qb + (size_t)(q0 + qt * 16 + q15) * C_ + g * 8);

  f32x4 o[4][2];
#pragma unroll
  for (int qt = 0; qt < 4; ++qt) o[qt][0] = o[qt][1] = (f32x4){0.f, 0.f, 0.f, 0.f};
  float l[4] = {0.f, 0.f, 0.f, 0.f};

#define LOADC(c_, K0, K1, V0, V1)                                              \
  {                                                                            \
    int k0_ = (c_) * 32;                                                       \
    K0 = *(const bf16x8*)(Kb + (size_t)(k0_ + q15) * C_ + g * 8);              \
    K1 = *(const bf16x8*)(Kb + (size_t)(k0_ + 16 + q15) * C_ + g * 8);         \
    const short* vp0_ = Vb + (size_t)(q15) * NS_ + k0_ + g * 4;                \
    const short* vp1_ = Vb + (size_t)(16 + q15) * NS_ + k0_ + g * 4;           \
    bf16x4 a0_ = *(const bf16x4*)(vp0_), b0_ = *(const bf16x4*)(vp0_ + 16);    \
    bf16x4 a1_ = *(const bf16x4*)(vp1_), b1_ = *(const bf16x4*)(vp1_ + 16);    \
    V0 = (bf16x8){a0_.x, a0_.y, a0_.z, a0_.w, b0_.x, b0_.y, b0_.z, b0_.w};     \
    V1 = (bf16x8){a1_.x, a1_.y, a1_.z, a1_.w, b1_.x, b1_.y, b1_.z, b1_.w};     \
  }

#define COMPUTEC(K0, K1, V0, V1)                                               \
  {                                                                            \
    _Pragma("unroll")                                                          \
    for (int qt = 0; qt < 4; ++qt) {                                           \
      f32x4 z_ = {0.f, 0.f, 0.f, 0.f};                                         \
      f32x4 t0 = MFMA(K0, qf[qt], z_);                                         \
      f32x4 t1 = MFMA(K1, qf[qt], z_);                                         \
      f32x4 e0, e1;                                                            \
      e0.x = EXP2(t0.x); e0.y = EXP2(t0.y); e0.z = EXP2(t0.z); e0.w = EXP2(t0.w);\
      e1.x = EXP2(t1.x); e1.y = EXP2(t1.y); e1.z = EXP2(t1.z); e1.w = EXP2(t1.w);\
      l[qt] += ((e0.x + e0.y) + (e0.z + e0.w)) + ((e1.x + e1.y) + (e1.z + e1.w));\
      union { unsigned u[4]; bf16x8 v; } pu;                                   \
      pu.u[0] = cvtpk(e0.x, e0.y);                                             \
      pu.u[1] = cvtpk(e0.z, e0.w);                                             \
      pu.u[2] = cvtpk(e1.x, e1.y);                                             \
      pu.u[3] = cvtpk(e1.z, e1.w);                                             \
      o[qt][0] = MFMA(V0, pu.v, o[qt][0]);                                     \
      o[qt][1] = MFMA(V1, pu.v, o[qt][1]);                                     \
    }                                                                          \
  }

  bf16x8 kA0, kA1, vA0, vA1, kB0, kB1, vB0, vB1;
  LOADC(0, kA0, kA1, vA0, vA1);
#pragma unroll
  for (int cp = 0; cp < 8; ++cp) {
    LOADC(2 * cp + 1, kB0, kB1, vB0, vB1);
    COMPUTEC(kA0, kA1, vA0, vA1);
    if (cp < 7) LOADC(2 * cp + 2, kA0, kA1, vA0, vA1);
    COMPUTEC(kB0, kB1, vB0, vB1);
  }
#undef LOADC
#undef COMPUTEC

  short* opS = s ? op1 : op0;
#pragma unroll
  for (int qt = 0; qt < 4; ++qt) {
    float lt = l[qt];
    lt += __shfl_xor(lt, 16);
    lt += __shfl_xor(lt, 32);
    int q = q0 + qt * 16 + q15;
    if (g == 0) lp[((size_t)(s * B_ + b) * HEADS_ + h) * NS_ + q] = lt;
#pragma unroll
    for (int dt = 0; dt < 2; ++dt) {
      f32x4 ov = o[qt][dt];
      bf16x4 s4 = {f2b(ov.x), f2b(ov.y), f2b(ov.z), f2b(ov.w)};
      *(bf16x4*)(opS + ((size_t)b * NS_ + q) * C_ + h * HD_ + dt * 16 + g * 4) = s4;
    }
  }
}

// ---------------------------------------------------------------------------
// merge: o = (op0 + op1) / (l0 + l1), out n-major bf16
// ---------------------------------------------------------------------------
__global__ __launch_bounds__(256) void attn_merge(
    const short* __restrict__ op0, const short* __restrict__ op1,
    const float* __restrict__ lp, short* __restrict__ on) {
  int idx = blockIdx.x * 256 + threadIdx.x;
  int c8 = idx % (C_ / 8);
  int q  = (idx / (C_ / 8)) % NS_;
  int b  = idx / ((C_ / 8) * NS_);
  int c0 = c8 * 8, h = c0 >> 5;
  size_t off = ((size_t)b * NS_ + q) * C_ + c0;
  bf16x8 a  = *(const bf16x8*)(op0 + off);
  bf16x8 bb = *(const bf16x8*)(op1 + off);
  float l = lp[((size_t)b * HEADS_ + h) * NS_ + q] +
            lp[((size_t)(B_ + b) * HEADS_ + h) * NS_ + q];
  float rl = 1.f / l;
  short r[8];
#pragma unroll
  for (int j = 0; j < 8; ++j) r[j] = f2b((b2f(a[j]) + b2f(bb[j])) * rl);
  *(bf16x8*)(on + off) = *(bf16x8*)r;
}

// ---------------------------------------------------------------------------
extern "C" void kernel_launch(void* const* d_in, const int* in_sizes, int n_in,
                              void* d_out, int out_size, void* d_ws, size_t ws_size,
                              hipStream_t stream) {
  const float* x1      = (const float*)d_in[0];
  const float* x2      = (const float*)d_in[1];
  const float* Wq      = (const float*)d_in[2];
  const float* bq      = (const float*)d_in[3];
  const float* Wk      = (const float*)d_in[4];
  const float* bk      = (const float*)d_in[5];
  const float* Wv      = (const float*)d_in[6];
  const float* bv      = (const float*)d_in[7];
  const float* Wo      = (const float*)d_in[8];
  const float* bo      = (const float*)d_in[9];
  const float* off_dw  = (const float*)d_in[10];
  const float* off_dwb = (const float*)d_in[11];
  const float* ln_g    = (const float*)d_in[12];
  const float* ln_b    = (const float*)d_in[13];
  const float* off_w   = (const float*)d_in[14];

  char* base = (char*)d_ws;
  const size_t SZ = (size_t)B_ * C_ * NS_;
  float* q_dC = (float*)base;                   // f32, dead after offsample3
  short* q_nC = (short*)(base + SZ * 4);
  short* samp = (short*)(base + SZ * 6);        // dead after k/v gemms
  short* k_nC = (short*)(base + SZ * 8);
  short* v_dN = (short*)(base + SZ * 10);
  short* o_nC = (short*)(base + SZ * 12);
  short* x1t  = (short*)(base + SZ * 14);       // dead after q gemm
  short* Wqb  = (short*)(base + SZ * 16);
  short* Wkb  = Wqb + C_ * C_;
  short* Wvb  = Wkb + C_ * C_;
  short* Wob  = Wvb + C_ * C_;
  // attention partials reuse dead regions:
  short* op0  = samp;               // SZ bf16
  short* op1  = x1t;                // SZ bf16
  float* lp   = q_dC;               // 2*B*H*NS f32 = 786 KB

  dim3 gg(NS_ / 128, C_ / 128, B_);   // (8, 3, 8)

  convw<<<dim3((C_ * C_ + 255) / 256, 4), 256, 0, stream>>>(
      Wq, Wk, Wv, Wo, Wqb, Wkb, Wvb, Wob, C_ * C_);
  transp<<<dim3(NS_ / 32, C_ / 32, B_), 256, 0, stream>>>(x1, x1t);
  gemm_nm<1><<<gg, 256, 0, stream>>>(x1t, Wqb, bq, nullptr, q_nC, q_dC);
  offsample3<<<dim3(B_ * GROUPS_, 64), 256, 0, stream>>>(
      q_dC, x2, off_dw, off_dwb, ln_g, ln_b, off_w, samp);
  gemm_nm<0><<<gg, 256, 0, stream>>>(samp, Wkb, bk, nullptr, k_nC, nullptr);
  gemm_nm<2><<<gg, 256, 0, stream>>>(samp, Wvb, bv, nullptr, v_dN, nullptr);
  attn_split<<<dim3(768), 256, 0, stream>>>(q_nC, k_nC, v_dN, op0, op1, lp);
  attn_merge<<<dim3(B_ * NS_ * (C_ / 8) / 256), 256, 0, stream>>>(op0, op1, lp, o_nC);
  gemm_nm<3><<<gg, 256, 0, stream>>>(o_nC, Wob, bo, x1, nullptr, (float*)d_out);
}

// Round 8
// 141.390 us; speedup vs baseline: 1.4681x; 1.1448x over previous
//
#include <hip/hip_runtime.h>
#include <math.h>

#define B_  8
#define C_  384
#define NS_ 1024
#define HEADS_ 12
#define HD_ 32
#define GROUPS_ 3
#define CG_ 128
#define EPS_ 1e-5f
// 1/sqrt(32) * log2(e)  (exp computed as exp2)
#define QSC2 (0.17677669529663687f * 1.4426950408889634f)

typedef __attribute__((ext_vector_type(8))) short bf16x8;
typedef __attribute__((ext_vector_type(4))) short bf16x4;
typedef __attribute__((ext_vector_type(4))) float f32x4;
typedef __attribute__((ext_vector_type(8))) __bf16 b8;

static __device__ __forceinline__ short f2b(float f) {
  union { float f; unsigned u; } v; v.f = f;
  unsigned r = v.u + 0x7fffu + ((v.u >> 16) & 1u);   // RNE
  return (short)(r >> 16);
}
static __device__ __forceinline__ float b2f(short s) {
  union { unsigned u; float f; } v; v.u = ((unsigned)(unsigned short)s) << 16;
  return v.f;
}

#if __has_builtin(__builtin_amdgcn_exp2f)
#define EXP2(x) __builtin_amdgcn_exp2f(x)
#else
#define EXP2(x) exp2f(x)
#endif

static __device__ __forceinline__ unsigned cvtpk(float lo, float hi) {
  unsigned r;
  asm("v_cvt_pk_bf16_f32 %0, %1, %2" : "=v"(r) : "v"(lo), "v"(hi));
  return r;
}

static __device__ __forceinline__ f32x4 MFMA(bf16x8 a, bf16x8 b, f32x4 c) {
  return __builtin_amdgcn_mfma_f32_16x16x32_bf16(
      __builtin_bit_cast(b8, a), __builtin_bit_cast(b8, b), c, 0, 0, 0);
}

// ---------------------------------------------------------------------------
// weight fp32 -> bf16 (4 matrices)
// ---------------------------------------------------------------------------
__global__ void convw(const float* __restrict__ s0, const float* __restrict__ s1,
                      const float* __restrict__ s2, const float* __restrict__ s3,
                      short* __restrict__ d0, short* __restrict__ d1,
                      short* __restrict__ d2, short* __restrict__ d3, int n) {
  int i = blockIdx.x * 256 + threadIdx.x;
  if (i >= n) return;
  const float* s = blockIdx.y == 0 ? s0 : blockIdx.y == 1 ? s1 : blockIdx.y == 2 ? s2 : s3;
  short*       d = blockIdx.y == 0 ? d0 : blockIdx.y == 1 ? d1 : blockIdx.y == 2 ? d2 : d3;
  d[i] = f2b(s[i]);
}

// ---------------------------------------------------------------------------
// x1 (B,C,NS) f32 -> x1t (B,NS,C) bf16
// ---------------------------------------------------------------------------
__global__ __launch_bounds__(256) void transp(const float* __restrict__ src,
                                              short* __restrict__ dst) {
  __shared__ float tl[32][33];
  int n0 = blockIdx.x * 32, c0 = blockIdx.y * 32, b = blockIdx.z;
  int tx = threadIdx.x & 31, ty = threadIdx.x >> 5;
#pragma unroll
  for (int i = 0; i < 4; ++i)
    tl[ty + 8 * i][tx] = src[((size_t)b * C_ + c0 + ty + 8 * i) * NS_ + n0 + tx];
  __syncthreads();
#pragma unroll
  for (int i = 0; i < 4; ++i)
    dst[((size_t)b * NS_ + n0 + ty + 8 * i) * C_ + c0 + tx] = f2b(tl[tx][ty + 8 * i]);
}

// ---------------------------------------------------------------------------
// MFMA GEMM, n-major activations (128x128 tile, 4 waves, 64x64/wave, acc 4x4)
// MODE 0: K-projection -> k_blk fragment-blocked layout (see attn_blk)
// MODE 1: outf d-major f32, outb n-major bf16 * QSC2    (q projection)
// MODE 2: V-projection -> v_blk fragment-blocked (sigma-permuted key order)
// MODE 3: outf d-major f32 + res      (final projection + residual)
//
// k_blk layout (shorts): [(b*12+h)*32 + chunk]*1024 + frag*512 + l*8 + j
//   holds K[key = chunk*32 + frag*16 + (l&15)][dim = (l>>4)*8 + j]
// v_blk layout (shorts): [(b*12+h)*32 + chunk]*1024 + dt*512 + l*8 + j
//   holds V[dim = dt*16 + (l&15)][key = chunk*32 + (j<4 ? 4*(l>>4)+j
//                                                      : 16+4*(l>>4)+j-4)]
// ---------------------------------------------------------------------------
template <int MODE>
__global__ __launch_bounds__(256) void gemm_nm(
    const short* __restrict__ A, const short* __restrict__ Wb,
    const float* __restrict__ bias, const float* __restrict__ res,
    short* __restrict__ outb, float* __restrict__ outf) {
  int b = blockIdx.z;
  int n0 = blockIdx.x * 128;
  int m0 = blockIdx.y * 128;
  int wv = threadIdx.x >> 6;
  int lane = threadIdx.x & 63;
  int g = lane >> 4, r15 = lane & 15;
  int wr = (wv >> 1) * 64, wc = (wv & 1) * 64;

  const short* Ab = A + (size_t)b * NS_ * C_;
  f32x4 acc[4][4];
#pragma unroll
  for (int i = 0; i < 4; ++i)
#pragma unroll
    for (int j = 0; j < 4; ++j) acc[i][j] = (f32x4){0.f, 0.f, 0.f, 0.f};

  for (int kc = 0; kc < C_; kc += 32) {
    bf16x8 af[4], bfr[4];
#pragma unroll
    for (int rt = 0; rt < 4; ++rt)
      af[rt] = *(const bf16x8*)(Ab + (size_t)(n0 + wr + rt * 16 + r15) * C_ + kc + g * 8);
#pragma unroll
    for (int ct = 0; ct < 4; ++ct)
      bfr[ct] = *(const bf16x8*)(Wb + (size_t)(m0 + wc + ct * 16 + r15) * C_ + kc + g * 8);
#pragma unroll
    for (int rt = 0; rt < 4; ++rt)
#pragma unroll
      for (int ct = 0; ct < 4; ++ct) acc[rt][ct] = MFMA(af[rt], bfr[ct], acc[rt][ct]);
  }

#pragma unroll
  for (int rt = 0; rt < 4; ++rt)
#pragma unroll
    for (int ct = 0; ct < 4; ++ct) {
      int m = m0 + wc + ct * 16 + r15;
      int nb = n0 + wr + rt * 16 + g * 4;     // nb % 4 == 0, (nb&15) in {0,4,8,12}
      float bv = bias[m];
      f32x4 v = acc[rt][ct];
      v.x += bv; v.y += bv; v.z += bv; v.w += bv;
      if (MODE == 1) {
        *(f32x4*)(outf + ((size_t)b * C_ + m) * NS_ + nb) = v;
        outb[((size_t)b * NS_ + nb + 0) * C_ + m] = f2b(v.x * QSC2);
        outb[((size_t)b * NS_ + nb + 1) * C_ + m] = f2b(v.y * QSC2);
        outb[((size_t)b * NS_ + nb + 2) * C_ + m] = f2b(v.z * QSC2);
        outb[((size_t)b * NS_ + nb + 3) * C_ + m] = f2b(v.w * QSC2);
      } else if (MODE == 0) {
        // k_blk: key = nb+jj, dim = m
        int h = m >> 5, dh = m & 31;
        size_t hb = ((size_t)(b * HEADS_ + h) * 32 + (nb >> 5)) * 1024 +
                    (((nb >> 4) & 1) ? 512 : 0);
        int base_l = (nb & 15) | ((dh >> 3) << 4);
        int jj = dh & 7;
        outb[hb + (size_t)(base_l + 0) * 8 + jj] = f2b(v.x);
        outb[hb + (size_t)(base_l + 1) * 8 + jj] = f2b(v.y);
        outb[hb + (size_t)(base_l + 2) * 8 + jj] = f2b(v.z);
        outb[hb + (size_t)(base_l + 3) * 8 + jj] = f2b(v.w);
      } else if (MODE == 2) {
        // v_blk: dim = m, keys nb..nb+3 (sigma order)
        int h = m >> 5, dh = m & 31;
        int dt = dh >> 4, q15v = dh & 15;
        int kk = nb & 31;
        int half = kk >> 4, gk = (kk & 15) >> 2;
        size_t off = ((size_t)(b * HEADS_ + h) * 32 + (nb >> 5)) * 1024 +
                     dt * 512 + (size_t)((q15v | (gk << 4))) * 8 + half * 4;
        bf16x4 s4 = {f2b(v.x), f2b(v.y), f2b(v.z), f2b(v.w)};
        *(bf16x4*)(outb + off) = s4;
      } else {
        const f32x4 rv = *(const f32x4*)(res + ((size_t)b * C_ + m) * NS_ + nb);
        v.x += rv.x; v.y += rv.y; v.z += rv.z; v.w += rv.w;
        *(f32x4*)(outf + ((size_t)b * C_ + m) * NS_ + nb) = v;
      }
    }
}

// ---------------------------------------------------------------------------
// fused depthwise 5x5 + LN + GELU + offset proj + bilinear sample.
// ---------------------------------------------------------------------------
__global__ __launch_bounds__(256) void offsample3(
    const float* __restrict__ qd, const float* __restrict__ x2,
    const float* __restrict__ dw, const float* __restrict__ dwb,
    const float* __restrict__ lng, const float* __restrict__ lnb,
    const float* __restrict__ offw, short* __restrict__ samp) {
  __shared__ float redS[4][16], redSS[4][16], redO0[4][16], redO1[4][16];
  int bg = blockIdx.x, t16 = blockIdx.y;
  int tid = threadIdx.x;
  int cc = tid >> 4, p = tid & 15;
  int wv = tid >> 6, lane = tid & 63;
  int n = t16 * 16 + p;
  int y = t16 >> 1;
  int x = ((t16 & 1) << 4) + p;
  int c0 = cc << 3;

  const float* qb = qd + (size_t)bg * CG_ * NS_;

  float a[8];
  float s = 0.f, ss = 0.f;
#pragma unroll
  for (int i = 0; i < 8; ++i) {
    int c = c0 + i;
    const float* qc = qb + (size_t)c * NS_;
    const float* wc = dw + c * 25;
    float acc = dwb[c];
#pragma unroll
    for (int dy = -2; dy <= 2; ++dy) {
      int yy = y + dy;
      if (yy < 0 || yy > 31) continue;
      const float* row = qc + yy * 32;
      const float* wr_ = wc + (dy + 2) * 5;
#pragma unroll
      for (int dx = -2; dx <= 2; ++dx) {
        int xx = x + dx;
        int xcl = min(max(xx, 0), 31);
        float v = row[xcl];
        if (xx != xcl) v = 0.f;
        acc = fmaf(v, wr_[dx + 2], acc);
      }
    }
    a[i] = acc;
    s += acc; ss += acc * acc;
  }

  s  += __shfl_xor(s, 16);  s  += __shfl_xor(s, 32);
  ss += __shfl_xor(ss, 16); ss += __shfl_xor(ss, 32);
  if (lane < 16) { redS[wv][lane] = s; redSS[wv][lane] = ss; }
  __syncthreads();
  float S  = (redS[0][p]  + redS[1][p])  + (redS[2][p]  + redS[3][p]);
  float SS = (redSS[0][p] + redSS[1][p]) + (redSS[2][p] + redSS[3][p]);
  float mu = S * (1.f / CG_);
  float var = SS * (1.f / CG_) - mu * mu;
  float rs = rsqrtf(var + EPS_);

  float o0 = 0.f, o1 = 0.f;
#pragma unroll
  for (int i = 0; i < 8; ++i) {
    int c = c0 + i;
    float z = (a[i] - mu) * rs * lng[c] + lnb[c];
    float u = z * fmaf(0.044715f * z, z, 1.f);
    float e = __expf(-1.5957691216057308f * u);
    float ge = z * __builtin_amdgcn_rcpf(1.f + e);
    o0 = fmaf(offw[c], ge, o0);
    o1 = fmaf(offw[CG_ + c], ge, o1);
  }
  o0 += __shfl_xor(o0, 16); o0 += __shfl_xor(o0, 32);
  o1 += __shfl_xor(o1, 16); o1 += __shfl_xor(o1, 32);
  if (lane < 16) { redO0[wv][lane] = o0; redO1[wv][lane] = o1; }
  __syncthreads();
  float off0 = (redO0[0][p] + redO0[1][p]) + (redO0[2][p] + redO0[3][p]);
  float off1 = (redO1[0][p] + redO1[1][p]) + (redO1[2][p] + redO1[3][p]);

  float gx = (x + 0.5f) * 0.0625f - 1.f;
  float gy = (y + 0.5f) * 0.0625f - 1.f;
  float px = fminf(fmaxf(off0 + gx, -1.f), 1.f);
  float py = fminf(fmaxf(off1 + gy, -1.f), 1.f);
  float ix = (px + 1.f) * 0.5f * 31.f;
  float iy = (py + 1.f) * 0.5f * 31.f;
  float x0f = floorf(ix), y0f = floorf(iy);
  float wx = ix - x0f, wy = iy - y0f;
  int x0 = min(max((int)x0f, 0), 31), x1i = min(x0 + 1, 31);
  int y0 = min(max((int)y0f, 0), 31), y1i = min(y0 + 1, 31);
  int i00 = y0 * 32 + x0,  i01 = y0 * 32 + x1i;
  int i10 = y1i * 32 + x0, i11 = y1i * 32 + x1i;
  float w00 = (1.f - wx) * (1.f - wy), w01 = wx * (1.f - wy);
  float w10 = (1.f - wx) * wy,         w11 = wx * wy;

  int b = bg / GROUPS_, gi = bg % GROUPS_;
  const float* xb = x2 + (size_t)bg * CG_ * NS_;
  short out8[8];
#pragma unroll
  for (int i = 0; i < 8; ++i) {
    const float* xc = xb + (size_t)(c0 + i) * NS_;
    float v = w00 * xc[i00] + w01 * xc[i01] + w10 * xc[i10] + w11 * xc[i11];
    out8[i] = f2b(v);
  }
  *(bf16x8*)(samp + ((size_t)b * NS_ + n) * C_ + gi * CG_ + c0) = *(bf16x8*)out8;
}

// ---------------------------------------------------------------------------
// Blocked-layout MFMA attention: per chunk, 4 perfectly-coalesced 1KB loads
// (lane l reads its own 16B fragment at base + l*16). 32 q/wave, split-K=2,
// XCD-locality swizzle, 1-deep A/B register prefetch. No-max softmax.
// ---------------------------------------------------------------------------
__global__ __launch_bounds__(256) void attn_blk(
    const short* __restrict__ qn, const short* __restrict__ kblk,
    const short* __restrict__ vblk, short* __restrict__ op0,
    short* __restrict__ op1, float* __restrict__ lp) {
  // grid 1536: L = (task%8) + 8*((task/8) + 24*qblk); task = bh*2+s
  int L = blockIdx.x;
  int tq = L >> 3;
  int task = (L & 7) + ((tq % 24) << 3);   // 0..191
  int qblk = tq / 24;                      // 0..7
  int bh = task >> 1, s = task & 1;
  int b = bh / HEADS_, h = bh % HEADS_;
  int wv = threadIdx.x >> 6, lane = threadIdx.x & 63;
  int g = lane >> 4, q15 = lane & 15;
  int q0 = qblk * 128 + wv * 32;

  const short* Qb = qn + (size_t)b * NS_ * C_ + h * HD_;
  const short* Kc = kblk + ((size_t)(b * HEADS_ + h) * 32 + s * 16) * 1024 + lane * 8;
  const short* Vc = vblk + ((size_t)(b * HEADS_ + h) * 32 + s * 16) * 1024 + lane * 8;

  bf16x8 qf[2];
  qf[0] = *(const bf16x8*)(Qb + (size_t)(q0 + q15) * C_ + g * 8);
  qf[1] = *(const bf16x8*)(Qb + (size_t)(q0 + 16 + q15) * C_ + g * 8);

  f32x4 o[2][2];
  o[0][0] = o[0][1] = o[1][0] = o[1][1] = (f32x4){0.f, 0.f, 0.f, 0.f};
  f32x4 lv[2];
  lv[0] = lv[1] = (f32x4){0.f, 0.f, 0.f, 0.f};

#define LOADC(c_, K0, K1, V0, V1)                                              \
  {                                                                            \
    K0 = *(const bf16x8*)(Kc + (c_) * 1024);                                   \
    K1 = *(const bf16x8*)(Kc + (c_) * 1024 + 512);                             \
    V0 = *(const bf16x8*)(Vc + (c_) * 1024);                                   \
    V1 = *(const bf16x8*)(Vc + (c_) * 1024 + 512);                             \
  }

#define COMPUTEC(K0, K1, V0, V1)                                               \
  {                                                                            \
    _Pragma("unroll")                                                          \
    for (int qt = 0; qt < 2; ++qt) {                                           \
      f32x4 z_ = {0.f, 0.f, 0.f, 0.f};                                         \
      f32x4 t0 = MFMA(K0, qf[qt], z_);                                         \
      f32x4 t1 = MFMA(K1, qf[qt], z_);                                         \
      f32x4 e0, e1;                                                            \
      e0.x = EXP2(t0.x); e0.y = EXP2(t0.y); e0.z = EXP2(t0.z); e0.w = EXP2(t0.w);\
      e1.x = EXP2(t1.x); e1.y = EXP2(t1.y); e1.z = EXP2(t1.z); e1.w = EXP2(t1.w);\
      lv[qt] += e0; lv[qt] += e1;                                              \
      union { unsigned u[4]; bf16x8 v; } pu;                                   \
      pu.u[0] = cvtpk(e0.x, e0.y);                                             \
      pu.u[1] = cvtpk(e0.z, e0.w);                                             \
      pu.u[2] = cvtpk(e1.x, e1.y);                                             \
      pu.u[3] = cvtpk(e1.z, e1.w);                                             \
      o[qt][0] = MFMA(V0, pu.v, o[qt][0]);                                     \
      o[qt][1] = MFMA(V1, pu.v, o[qt][1]);                                     \
    }                                                                          \
  }

  bf16x8 kA0, kA1, vA0, vA1, kB0, kB1, vB0, vB1;
  LOADC(0, kA0, kA1, vA0, vA1);
#pragma unroll
  for (int cp = 0; cp < 8; ++cp) {
    LOADC(2 * cp + 1, kB0, kB1, vB0, vB1);
    COMPUTEC(kA0, kA1, vA0, vA1);
    if (cp < 7) LOADC(2 * cp + 2, kA0, kA1, vA0, vA1);
    COMPUTEC(kB0, kB1, vB0, vB1);
  }
#undef LOADC
#undef COMPUTEC

  short* opS = s ? op1 : op0;
#pragma unroll
  for (int qt = 0; qt < 2; ++qt) {
    float lt = (lv[qt].x + lv[qt].y) + (lv[qt].z + lv[qt].w);
    lt += __shfl_xor(lt, 16);
    lt += __shfl_xor(lt, 32);
    int q = q0 + qt * 16 + q15;
    if (g == 0) lp[((size_t)(s * B_ + b) * HEADS_ + h) * NS_ + q] = lt;
#pragma unroll
    for (int dt = 0; dt < 2; ++dt) {
      f32x4 ov = o[qt][dt];
      bf16x4 s4 = {f2b(ov.x), f2b(ov.y), f2b(ov.z), f2b(ov.w)};
      *(bf16x4*)(opS + ((size_t)b * NS_ + q) * C_ + h * HD_ + dt * 16 + g * 4) = s4;
    }
  }
}

// ---------------------------------------------------------------------------
// merge: o = (op0 + op1) / (l0 + l1), out n-major bf16
// ---------------------------------------------------------------------------
__global__ __launch_bounds__(256) void attn_merge(
    const short* __restrict__ op0, const short* __restrict__ op1,
    const float* __restrict__ lp, short* __restrict__ on) {
  int idx = blockIdx.x * 256 + threadIdx.x;
  int c8 = idx % (C_ / 8);
  int q  = (idx / (C_ / 8)) % NS_;
  int b  = idx / ((C_ / 8) * NS_);
  int c0 = c8 * 8, h = c0 >> 5;
  size_t off = ((size_t)b * NS_ + q) * C_ + c0;
  bf16x8 a  = *(const bf16x8*)(op0 + off);
  bf16x8 bb = *(const bf16x8*)(op1 + off);
  float l = lp[((size_t)b * HEADS_ + h) * NS_ + q] +
            lp[((size_t)(B_ + b) * HEADS_ + h) * NS_ + q];
  float rl = 1.f / l;
  short r[8];
#pragma unroll
  for (int j = 0; j < 8; ++j) r[j] = f2b((b2f(a[j]) + b2f(bb[j])) * rl);
  *(bf16x8*)(on + off) = *(bf16x8*)r;
}

// ---------------------------------------------------------------------------
extern "C" void kernel_launch(void* const* d_in, const int* in_sizes, int n_in,
                              void* d_out, int out_size, void* d_ws, size_t ws_size,
                              hipStream_t stream) {
  const float* x1      = (const float*)d_in[0];
  const float* x2      = (const float*)d_in[1];
  const float* Wq      = (const float*)d_in[2];
  const float* bq      = (const float*)d_in[3];
  const float* Wk      = (const float*)d_in[4];
  const float* bk      = (const float*)d_in[5];
  const float* Wv      = (const float*)d_in[6];
  const float* bv      = (const float*)d_in[7];
  const float* Wo      = (const float*)d_in[8];
  const float* bo      = (const float*)d_in[9];
  const float* off_dw  = (const float*)d_in[10];
  const float* off_dwb = (const float*)d_in[11];
  const float* ln_g    = (const float*)d_in[12];
  const float* ln_b    = (const float*)d_in[13];
  const float* off_w   = (const float*)d_in[14];

  char* base = (char*)d_ws;
  const size_t SZ = (size_t)B_ * C_ * NS_;
  float* q_dC  = (float*)base;                   // f32, dead after offsample3
  short* q_nC  = (short*)(base + SZ * 4);
  short* samp  = (short*)(base + SZ * 6);        // dead after k/v gemms
  short* k_blk = (short*)(base + SZ * 8);
  short* v_blk = (short*)(base + SZ * 10);
  short* o_nC  = (short*)(base + SZ * 12);
  short* x1t   = (short*)(base + SZ * 14);       // dead after q gemm
  short* Wqb   = (short*)(base + SZ * 16);
  short* Wkb   = Wqb + C_ * C_;
  short* Wvb   = Wkb + C_ * C_;
  short* Wob   = Wvb + C_ * C_;
  // attention partials reuse dead regions:
  short* op0   = samp;               // SZ bf16
  short* op1   = x1t;                // SZ bf16
  float* lp    = q_dC;               // 2*B*H*NS f32 = 786 KB

  dim3 gg(NS_ / 128, C_ / 128, B_);   // (8, 3, 8)

  convw<<<dim3((C_ * C_ + 255) / 256, 4), 256, 0, stream>>>(
      Wq, Wk, Wv, Wo, Wqb, Wkb, Wvb, Wob, C_ * C_);
  transp<<<dim3(NS_ / 32, C_ / 32, B_), 256, 0, stream>>>(x1, x1t);
  gemm_nm<1><<<gg, 256, 0, stream>>>(x1t, Wqb, bq, nullptr, q_nC, q_dC);
  offsample3<<<dim3(B_ * GROUPS_, 64), 256, 0, stream>>>(
      q_dC, x2, off_dw, off_dwb, ln_g, ln_b, off_w, samp);
  gemm_nm<0><<<gg, 256, 0, stream>>>(samp, Wkb, bk, nullptr, k_blk, nullptr);
  gemm_nm<2><<<gg, 256, 0, stream>>>(samp, Wvb, bv, nullptr, v_blk, nullptr);
  attn_blk<<<dim3(1536), 256, 0, stream>>>(q_nC, k_blk, v_blk, op0, op1, lp);
  attn_merge<<<dim3(B_ * NS_ * (C_ / 8) / 256), 256, 0, stream>>>(op0, op1, lp, o_nC);
  gemm_nm<3><<<gg, 256, 0, stream>>>(o_nC, Wob, bo, x1, nullptr, (float*)d_out);
}

// Round 9
// 136.218 us; speedup vs baseline: 1.5238x; 1.0380x over previous
//
#include <hip/hip_runtime.h>
#include <math.h>

#define B_  8
#define C_  384
#define NS_ 1024
#define HEADS_ 12
#define HD_ 32
#define GROUPS_ 3
#define CG_ 128
#define EPS_ 1e-5f
// 1/sqrt(32) * log2(e)  (exp computed as exp2)
#define QSC2 (0.17677669529663687f * 1.4426950408889634f)

typedef __attribute__((ext_vector_type(8))) short bf16x8;
typedef __attribute__((ext_vector_type(4))) short bf16x4;
typedef __attribute__((ext_vector_type(4))) float f32x4;
typedef __attribute__((ext_vector_type(8))) __bf16 b8;

static __device__ __forceinline__ short f2b(float f) {
  union { float f; unsigned u; } v; v.f = f;
  unsigned r = v.u + 0x7fffu + ((v.u >> 16) & 1u);   // RNE
  return (short)(r >> 16);
}
static __device__ __forceinline__ float b2f(short s) {
  union { unsigned u; float f; } v; v.u = ((unsigned)(unsigned short)s) << 16;
  return v.f;
}

#if __has_builtin(__builtin_amdgcn_exp2f)
#define EXP2(x) __builtin_amdgcn_exp2f(x)
#else
#define EXP2(x) exp2f(x)
#endif

static __device__ __forceinline__ unsigned cvtpk(float lo, float hi) {
  unsigned r;
  asm("v_cvt_pk_bf16_f32 %0, %1, %2" : "=v"(r) : "v"(lo), "v"(hi));
  return r;
}

static __device__ __forceinline__ f32x4 MFMA(bf16x8 a, bf16x8 b, f32x4 c) {
  return __builtin_amdgcn_mfma_f32_16x16x32_bf16(
      __builtin_bit_cast(b8, a), __builtin_bit_cast(b8, b), c, 0, 0, 0);
}

// ---------------------------------------------------------------------------
// weight fp32 -> bf16 (4 matrices)
// ---------------------------------------------------------------------------
__global__ void convw(const float* __restrict__ s0, const float* __restrict__ s1,
                      const float* __restrict__ s2, const float* __restrict__ s3,
                      short* __restrict__ d0, short* __restrict__ d1,
                      short* __restrict__ d2, short* __restrict__ d3, int n) {
  int i = blockIdx.x * 256 + threadIdx.x;
  if (i >= n) return;
  const float* s = blockIdx.y == 0 ? s0 : blockIdx.y == 1 ? s1 : blockIdx.y == 2 ? s2 : s3;
  short*       d = blockIdx.y == 0 ? d0 : blockIdx.y == 1 ? d1 : blockIdx.y == 2 ? d2 : d3;
  d[i] = f2b(s[i]);
}

// ---------------------------------------------------------------------------
// x1 (B,C,NS) f32 -> x1t (B,NS,C) bf16
// ---------------------------------------------------------------------------
__global__ __launch_bounds__(256) void transp(const float* __restrict__ src,
                                              short* __restrict__ dst) {
  __shared__ float tl[32][33];
  int n0 = blockIdx.x * 32, c0 = blockIdx.y * 32, b = blockIdx.z;
  int tx = threadIdx.x & 31, ty = threadIdx.x >> 5;
#pragma unroll
  for (int i = 0; i < 4; ++i)
    tl[ty + 8 * i][tx] = src[((size_t)b * C_ + c0 + ty + 8 * i) * NS_ + n0 + tx];
  __syncthreads();
#pragma unroll
  for (int i = 0; i < 4; ++i)
    dst[((size_t)b * NS_ + n0 + ty + 8 * i) * C_ + c0 + tx] = f2b(tl[tx][ty + 8 * i]);
}

// ---------------------------------------------------------------------------
// prefetch helpers for the GEMM K-loop
// ---------------------------------------------------------------------------
#define GLOADA(kc_, AF)                                                        \
  _Pragma("unroll")                                                            \
  for (int rt = 0; rt < 4; ++rt)                                               \
    AF[rt] = *(const bf16x8*)(Ab + (size_t)(n0 + wr + rt * 16 + r15) * C_ +    \
                              (kc_) + g * 8);
#define GLOADB(kc_, BF, WP, MOFF)                                              \
  _Pragma("unroll")                                                            \
  for (int ct = 0; ct < 4; ++ct)                                               \
    BF[ct] = *(const bf16x8*)((WP) + (size_t)((MOFF) + ct * 16 + r15) * C_ +   \
                              (kc_) + g * 8);
#define GMFMA(AF, BF)                                                          \
  _Pragma("unroll")                                                            \
  for (int rt = 0; rt < 4; ++rt)                                               \
    _Pragma("unroll")                                                          \
    for (int ct = 0; ct < 4; ++ct) acc[rt][ct] = MFMA(AF[rt], BF[ct], acc[rt][ct]);

// ---------------------------------------------------------------------------
// MFMA GEMM, n-major activations (128x128 tile, 4 waves, 64x64/wave, acc 4x4)
// 1-deep register prefetch on the K-loop.
// MODE 1: outf d-major f32, outb n-major bf16 * QSC2    (q projection)
// MODE 3: outf d-major f32 + res      (final projection + residual)
// ---------------------------------------------------------------------------
template <int MODE>
__global__ __launch_bounds__(256) void gemm_nm(
    const short* __restrict__ A, const short* __restrict__ Wb,
    const float* __restrict__ bias, const float* __restrict__ res,
    short* __restrict__ outb, float* __restrict__ outf) {
  int b = blockIdx.z;
  int n0 = blockIdx.x * 128;
  int m0 = blockIdx.y * 128;
  int wv = threadIdx.x >> 6;
  int lane = threadIdx.x & 63;
  int g = lane >> 4, r15 = lane & 15;
  int wr = (wv >> 1) * 64, wc = (wv & 1) * 64;

  const short* Ab = A + (size_t)b * NS_ * C_;
  f32x4 acc[4][4];
#pragma unroll
  for (int i = 0; i < 4; ++i)
#pragma unroll
    for (int j = 0; j < 4; ++j) acc[i][j] = (f32x4){0.f, 0.f, 0.f, 0.f};

  bf16x8 afA[4], bfA[4], afB[4], bfB[4];
  GLOADA(0, afA); GLOADB(0, bfA, Wb, m0 + wc);
#pragma unroll
  for (int cp = 0; cp < 6; ++cp) {
    GLOADA(64 * cp + 32, afB); GLOADB(64 * cp + 32, bfB, Wb, m0 + wc);
    GMFMA(afA, bfA);
    if (cp < 5) { GLOADA(64 * cp + 64, afA); GLOADB(64 * cp + 64, bfA, Wb, m0 + wc); }
    GMFMA(afB, bfB);
  }

#pragma unroll
  for (int rt = 0; rt < 4; ++rt)
#pragma unroll
    for (int ct = 0; ct < 4; ++ct) {
      int m = m0 + wc + ct * 16 + r15;
      int nb = n0 + wr + rt * 16 + g * 4;
      float bv = bias[m];
      f32x4 v = acc[rt][ct];
      v.x += bv; v.y += bv; v.z += bv; v.w += bv;
      if (MODE == 1) {
        *(f32x4*)(outf + ((size_t)b * C_ + m) * NS_ + nb) = v;
        outb[((size_t)b * NS_ + nb + 0) * C_ + m] = f2b(v.x * QSC2);
        outb[((size_t)b * NS_ + nb + 1) * C_ + m] = f2b(v.y * QSC2);
        outb[((size_t)b * NS_ + nb + 2) * C_ + m] = f2b(v.z * QSC2);
        outb[((size_t)b * NS_ + nb + 3) * C_ + m] = f2b(v.w * QSC2);
      } else {
        const f32x4 rv = *(const f32x4*)(res + ((size_t)b * C_ + m) * NS_ + nb);
        v.x += rv.x; v.y += rv.y; v.z += rv.z; v.w += rv.w;
        *(f32x4*)(outf + ((size_t)b * C_ + m) * NS_ + nb) = v;
      }
    }
}

// ---------------------------------------------------------------------------
// Fused K+V projection GEMM. Block = 128 n x 64 m, computing BOTH Wk and Wv
// rows m0..m0+64 (waves wv&1: 0 -> K, 1 -> V). Shares the A operand -> half
// the A traffic of two separate GEMMs; 384 blocks. 1-deep prefetch.
// Outputs in attention fragment-blocked layouts (see attn_blk).
// ---------------------------------------------------------------------------
__global__ __launch_bounds__(256) void gemm_kv(
    const short* __restrict__ A, const short* __restrict__ Wkb,
    const short* __restrict__ Wvb, const float* __restrict__ bkv,
    const float* __restrict__ bvv, short* __restrict__ kblk,
    short* __restrict__ vblk) {
  int b = blockIdx.z;
  int n0 = blockIdx.x * 128;
  int m0 = blockIdx.y * 64;
  int wv = threadIdx.x >> 6;
  int lane = threadIdx.x & 63;
  int g = lane >> 4, r15 = lane & 15;
  int wr = (wv >> 1) * 64;
  int isv = wv & 1;
  const short* Wsel = isv ? Wvb : Wkb;
  const float* bsel = isv ? bvv : bkv;

  const short* Ab = A + (size_t)b * NS_ * C_;
  f32x4 acc[4][4];
#pragma unroll
  for (int i = 0; i < 4; ++i)
#pragma unroll
    for (int j = 0; j < 4; ++j) acc[i][j] = (f32x4){0.f, 0.f, 0.f, 0.f};

  bf16x8 afA[4], bfA[4], afB[4], bfB[4];
  GLOADA(0, afA); GLOADB(0, bfA, Wsel, m0);
#pragma unroll
  for (int cp = 0; cp < 6; ++cp) {
    GLOADA(64 * cp + 32, afB); GLOADB(64 * cp + 32, bfB, Wsel, m0);
    GMFMA(afA, bfA);
    if (cp < 5) { GLOADA(64 * cp + 64, afA); GLOADB(64 * cp + 64, bfA, Wsel, m0); }
    GMFMA(afB, bfB);
  }

#pragma unroll
  for (int rt = 0; rt < 4; ++rt)
#pragma unroll
    for (int ct = 0; ct < 4; ++ct) {
      int m = m0 + ct * 16 + r15;
      int nb = n0 + wr + rt * 16 + g * 4;
      float bv = bsel[m];
      f32x4 v = acc[rt][ct];
      v.x += bv; v.y += bv; v.z += bv; v.w += bv;
      int h = m >> 5, dh = m & 31;
      if (!isv) {
        // k_blk: key = nb+i, dim = m
        size_t hb = ((size_t)(b * HEADS_ + h) * 32 + (nb >> 5)) * 1024 +
                    (((nb >> 4) & 1) ? 512 : 0);
        int base_l = (nb & 15) | ((dh >> 3) << 4);
        int jj = dh & 7;
        kblk[hb + (size_t)(base_l + 0) * 8 + jj] = f2b(v.x);
        kblk[hb + (size_t)(base_l + 1) * 8 + jj] = f2b(v.y);
        kblk[hb + (size_t)(base_l + 2) * 8 + jj] = f2b(v.z);
        kblk[hb + (size_t)(base_l + 3) * 8 + jj] = f2b(v.w);
      } else {
        // v_blk: dim = m, keys nb..nb+3 (sigma order)
        int dt = dh >> 4, q15v = dh & 15;
        int kk = nb & 31;
        int half = kk >> 4, gk = (kk & 15) >> 2;
        size_t off = ((size_t)(b * HEADS_ + h) * 32 + (nb >> 5)) * 1024 +
                     dt * 512 + (size_t)((q15v | (gk << 4))) * 8 + half * 4;
        bf16x4 s4 = {f2b(v.x), f2b(v.y), f2b(v.z), f2b(v.w)};
        *(bf16x4*)(vblk + off) = s4;
      }
    }
}

// ---------------------------------------------------------------------------
// fused depthwise 5x5 + LN + GELU + offset proj + bilinear sample.
// ---------------------------------------------------------------------------
__global__ __launch_bounds__(256) void offsample3(
    const float* __restrict__ qd, const float* __restrict__ x2,
    const float* __restrict__ dw, const float* __restrict__ dwb,
    const float* __restrict__ lng, const float* __restrict__ lnb,
    const float* __restrict__ offw, short* __restrict__ samp) {
  __shared__ float redS[4][16], redSS[4][16], redO0[4][16], redO1[4][16];
  int bg = blockIdx.x, t16 = blockIdx.y;
  int tid = threadIdx.x;
  int cc = tid >> 4, p = tid & 15;
  int wv = tid >> 6, lane = tid & 63;
  int n = t16 * 16 + p;
  int y = t16 >> 1;
  int x = ((t16 & 1) << 4) + p;
  int c0 = cc << 3;

  const float* qb = qd + (size_t)bg * CG_ * NS_;

  float a[8];
  float s = 0.f, ss = 0.f;
#pragma unroll
  for (int i = 0; i < 8; ++i) {
    int c = c0 + i;
    const float* qc = qb + (size_t)c * NS_;
    const float* wc = dw + c * 25;
    float acc = dwb[c];
#pragma unroll
    for (int dy = -2; dy <= 2; ++dy) {
      int yy = y + dy;
      if (yy < 0 || yy > 31) continue;
      const float* row = qc + yy * 32;
      const float* wr_ = wc + (dy + 2) * 5;
#pragma unroll
      for (int dx = -2; dx <= 2; ++dx) {
        int xx = x + dx;
        int xcl = min(max(xx, 0), 31);
        float v = row[xcl];
        if (xx != xcl) v = 0.f;
        acc = fmaf(v, wr_[dx + 2], acc);
      }
    }
    a[i] = acc;
    s += acc; ss += acc * acc;
  }

  s  += __shfl_xor(s, 16);  s  += __shfl_xor(s, 32);
  ss += __shfl_xor(ss, 16); ss += __shfl_xor(ss, 32);
  if (lane < 16) { redS[wv][lane] = s; redSS[wv][lane] = ss; }
  __syncthreads();
  float S  = (redS[0][p]  + redS[1][p])  + (redS[2][p]  + redS[3][p]);
  float SS = (redSS[0][p] + redSS[1][p]) + (redSS[2][p] + redSS[3][p]);
  float mu = S * (1.f / CG_);
  float var = SS * (1.f / CG_) - mu * mu;
  float rs = rsqrtf(var + EPS_);

  float o0 = 0.f, o1 = 0.f;
#pragma unroll
  for (int i = 0; i < 8; ++i) {
    int c = c0 + i;
    float z = (a[i] - mu) * rs * lng[c] + lnb[c];
    float u = z * fmaf(0.044715f * z, z, 1.f);
    float e = __expf(-1.5957691216057308f * u);
    float ge = z * __builtin_amdgcn_rcpf(1.f + e);
    o0 = fmaf(offw[c], ge, o0);
    o1 = fmaf(offw[CG_ + c], ge, o1);
  }
  o0 += __shfl_xor(o0, 16); o0 += __shfl_xor(o0, 32);
  o1 += __shfl_xor(o1, 16); o1 += __shfl_xor(o1, 32);
  if (lane < 16) { redO0[wv][lane] = o0; redO1[wv][lane] = o1; }
  __syncthreads();
  float off0 = (redO0[0][p] + redO0[1][p]) + (redO0[2][p] + redO0[3][p]);
  float off1 = (redO1[0][p] + redO1[1][p]) + (redO1[2][p] + redO1[3][p]);

  float gx = (x + 0.5f) * 0.0625f - 1.f;
  float gy = (y + 0.5f) * 0.0625f - 1.f;
  float px = fminf(fmaxf(off0 + gx, -1.f), 1.f);
  float py = fminf(fmaxf(off1 + gy, -1.f), 1.f);
  float ix = (px + 1.f) * 0.5f * 31.f;
  float iy = (py + 1.f) * 0.5f * 31.f;
  float x0f = floorf(ix), y0f = floorf(iy);
  float wx = ix - x0f, wy = iy - y0f;
  int x0 = min(max((int)x0f, 0), 31), x1i = min(x0 + 1, 31);
  int y0 = min(max((int)y0f, 0), 31), y1i = min(y0 + 1, 31);
  int i00 = y0 * 32 + x0,  i01 = y0 * 32 + x1i;
  int i10 = y1i * 32 + x0, i11 = y1i * 32 + x1i;
  float w00 = (1.f - wx) * (1.f - wy), w01 = wx * (1.f - wy);
  float w10 = (1.f - wx) * wy,         w11 = wx * wy;

  int b = bg / GROUPS_, gi = bg % GROUPS_;
  const float* xb = x2 + (size_t)bg * CG_ * NS_;
  short out8[8];
#pragma unroll
  for (int i = 0; i < 8; ++i) {
    const float* xc = xb + (size_t)(c0 + i) * NS_;
    float v = w00 * xc[i00] + w01 * xc[i01] + w10 * xc[i10] + w11 * xc[i11];
    out8[i] = f2b(v);
  }
  *(bf16x8*)(samp + ((size_t)b * NS_ + n) * C_ + gi * CG_ + c0) = *(bf16x8*)out8;
}

// ---------------------------------------------------------------------------
// Blocked-layout MFMA attention: per chunk, 4 perfectly-coalesced 1KB loads
// (lane l reads its own 16B fragment at base + l*16). 32 q/wave, split-K=2,
// XCD-locality swizzle, 1-deep A/B register prefetch. No-max softmax.
// ---------------------------------------------------------------------------
__global__ __launch_bounds__(256) void attn_blk(
    const short* __restrict__ qn, const short* __restrict__ kblk,
    const short* __restrict__ vblk, short* __restrict__ op0,
    short* __restrict__ op1, float* __restrict__ lp) {
  // grid 1536: L = (task%8) + 8*((task/8) + 24*qblk); task = bh*2+s
  int L = blockIdx.x;
  int tq = L >> 3;
  int task = (L & 7) + ((tq % 24) << 3);   // 0..191
  int qblk = tq / 24;                      // 0..7
  int bh = task >> 1, s = task & 1;
  int b = bh / HEADS_, h = bh % HEADS_;
  int wv = threadIdx.x >> 6, lane = threadIdx.x & 63;
  int g = lane >> 4, q15 = lane & 15;
  int q0 = qblk * 128 + wv * 32;

  const short* Qb = qn + (size_t)b * NS_ * C_ + h * HD_;
  const short* Kc = kblk + ((size_t)(b * HEADS_ + h) * 32 + s * 16) * 1024 + lane * 8;
  const short* Vc = vblk + ((size_t)(b * HEADS_ + h) * 32 + s * 16) * 1024 + lane * 8;

  bf16x8 qf[2];
  qf[0] = *(const bf16x8*)(Qb + (size_t)(q0 + q15) * C_ + g * 8);
  qf[1] = *(const bf16x8*)(Qb + (size_t)(q0 + 16 + q15) * C_ + g * 8);

  f32x4 o[2][2];
  o[0][0] = o[0][1] = o[1][0] = o[1][1] = (f32x4){0.f, 0.f, 0.f, 0.f};
  f32x4 lv[2];
  lv[0] = lv[1] = (f32x4){0.f, 0.f, 0.f, 0.f};

#define LOADC(c_, K0, K1, V0, V1)                                              \
  {                                                                            \
    K0 = *(const bf16x8*)(Kc + (c_) * 1024);                                   \
    K1 = *(const bf16x8*)(Kc + (c_) * 1024 + 512);                             \
    V0 = *(const bf16x8*)(Vc + (c_) * 1024);                                   \
    V1 = *(const bf16x8*)(Vc + (c_) * 1024 + 512);                             \
  }

#define COMPUTEC(K0, K1, V0, V1)                                               \
  {                                                                            \
    _Pragma("unroll")                                                          \
    for (int qt = 0; qt < 2; ++qt) {                                           \
      f32x4 z_ = {0.f, 0.f, 0.f, 0.f};                                         \
      f32x4 t0 = MFMA(K0, qf[qt], z_);                                         \
      f32x4 t1 = MFMA(K1, qf[qt], z_);                                         \
      f32x4 e0, e1;                                                            \
      e0.x = EXP2(t0.x); e0.y = EXP2(t0.y); e0.z = EXP2(t0.z); e0.w = EXP2(t0.w);\
      e1.x = EXP2(t1.x); e1.y = EXP2(t1.y); e1.z = EXP2(t1.z); e1.w = EXP2(t1.w);\
      lv[qt] += e0; lv[qt] += e1;                                              \
      union { unsigned u[4]; bf16x8 v; } pu;                                   \
      pu.u[0] = cvtpk(e0.x, e0.y);                                             \
      pu.u[1] = cvtpk(e0.z, e0.w);                                             \
      pu.u[2] = cvtpk(e1.x, e1.y);                                             \
      pu.u[3] = cvtpk(e1.z, e1.w);                                             \
      o[qt][0] = MFMA(V0, pu.v, o[qt][0]);                                     \
      o[qt][1] = MFMA(V1, pu.v, o[qt][1]);                                     \
    }                                                                          \
  }

  bf16x8 kA0, kA1, vA0, vA1, kB0, kB1, vB0, vB1;
  LOADC(0, kA0, kA1, vA0, vA1);
#pragma unroll
  for (int cp = 0; cp < 8; ++cp) {
    LOADC(2 * cp + 1, kB0, kB1, vB0, vB1);
    COMPUTEC(kA0, kA1, vA0, vA1);
    if (cp < 7) LOADC(2 * cp + 2, kA0, kA1, vA0, vA1);
    COMPUTEC(kB0, kB1, vB0, vB1);
  }
#undef LOADC
#undef COMPUTEC

  short* opS = s ? op1 : op0;
#pragma unroll
  for (int qt = 0; qt < 2; ++qt) {
    float lt = (lv[qt].x + lv[qt].y) + (lv[qt].z + lv[qt].w);
    lt += __shfl_xor(lt, 16);
    lt += __shfl_xor(lt, 32);
    int q = q0 + qt * 16 + q15;
    if (g == 0) lp[((size_t)(s * B_ + b) * HEADS_ + h) * NS_ + q] = lt;
#pragma unroll
    for (int dt = 0; dt < 2; ++dt) {
      f32x4 ov = o[qt][dt];
      bf16x4 s4 = {f2b(ov.x), f2b(ov.y), f2b(ov.z), f2b(ov.w)};
      *(bf16x4*)(opS + ((size_t)b * NS_ + q) * C_ + h * HD_ + dt * 16 + g * 4) = s4;
    }
  }
}

// ---------------------------------------------------------------------------
// merge: o = (op0 + op1) / (l0 + l1), out n-major bf16
// ---------------------------------------------------------------------------
__global__ __launch_bounds__(256) void attn_merge(
    const short* __restrict__ op0, const short* __restrict__ op1,
    const float* __restrict__ lp, short* __restrict__ on) {
  int idx = blockIdx.x * 256 + threadIdx.x;
  int c8 = idx % (C_ / 8);
  int q  = (idx / (C_ / 8)) % NS_;
  int b  = idx / ((C_ / 8) * NS_);
  int c0 = c8 * 8, h = c0 >> 5;
  size_t off = ((size_t)b * NS_ + q) * C_ + c0;
  bf16x8 a  = *(const bf16x8*)(op0 + off);
  bf16x8 bb = *(const bf16x8*)(op1 + off);
  float l = lp[((size_t)b * HEADS_ + h) * NS_ + q] +
            lp[((size_t)(B_ + b) * HEADS_ + h) * NS_ + q];
  float rl = 1.f / l;
  short r[8];
#pragma unroll
  for (int j = 0; j < 8; ++j) r[j] = f2b((b2f(a[j]) + b2f(bb[j])) * rl);
  *(bf16x8*)(on + off) = *(bf16x8*)r;
}

// ---------------------------------------------------------------------------
extern "C" void kernel_launch(void* const* d_in, const int* in_sizes, int n_in,
                              void* d_out, int out_size, void* d_ws, size_t ws_size,
                              hipStream_t stream) {
  const float* x1      = (const float*)d_in[0];
  const float* x2      = (const float*)d_in[1];
  const float* Wq      = (const float*)d_in[2];
  const float* bq      = (const float*)d_in[3];
  const float* Wk      = (const float*)d_in[4];
  const float* bk      = (const float*)d_in[5];
  const float* Wv      = (const float*)d_in[6];
  const float* bv      = (const float*)d_in[7];
  const float* Wo      = (const float*)d_in[8];
  const float* bo      = (const float*)d_in[9];
  const float* off_dw  = (const float*)d_in[10];
  const float* off_dwb = (const float*)d_in[11];
  const float* ln_g    = (const float*)d_in[12];
  const float* ln_b    = (const float*)d_in[13];
  const float* off_w   = (const float*)d_in[14];

  char* base = (char*)d_ws;
  const size_t SZ = (size_t)B_ * C_ * NS_;
  float* q_dC  = (float*)base;                   // f32, dead after offsample3
  short* q_nC  = (short*)(base + SZ * 4);
  short* samp  = (short*)(base + SZ * 6);        // dead after k/v gemm
  short* k_blk = (short*)(base + SZ * 8);
  short* v_blk = (short*)(base + SZ * 10);
  short* o_nC  = (short*)(base + SZ * 12);
  short* x1t   = (short*)(base + SZ * 14);       // dead after q gemm
  short* Wqb   = (short*)(base + SZ * 16);
  short* Wkb   = Wqb + C_ * C_;
  short* Wvb   = Wkb + C_ * C_;
  short* Wob   = Wvb + C_ * C_;
  // attention partials reuse dead regions:
  short* op0   = samp;               // SZ bf16
  short* op1   = x1t;                // SZ bf16
  float* lp    = q_dC;               // 2*B*H*NS f32 = 786 KB

  dim3 gg(NS_ / 128, C_ / 128, B_);   // (8, 3, 8)

  convw<<<dim3((C_ * C_ + 255) / 256, 4), 256, 0, stream>>>(
      Wq, Wk, Wv, Wo, Wqb, Wkb, Wvb, Wob, C_ * C_);
  transp<<<dim3(NS_ / 32, C_ / 32, B_), 256, 0, stream>>>(x1, x1t);
  gemm_nm<1><<<gg, 256, 0, stream>>>(x1t, Wqb, bq, nullptr, q_nC, q_dC);
  offsample3<<<dim3(B_ * GROUPS_, 64), 256, 0, stream>>>(
      q_dC, x2, off_dw, off_dwb, ln_g, ln_b, off_w, samp);
  gemm_kv<<<dim3(NS_ / 128, C_ / 64, B_), 256, 0, stream>>>(
      samp, Wkb, Wvb, bk, bv, k_blk, v_blk);
  attn_blk<<<dim3(1536), 256, 0, stream>>>(q_nC, k_blk, v_blk, op0, op1, lp);
  attn_merge<<<dim3(B_ * NS_ * (C_ / 8) / 256), 256, 0, stream>>>(op0, op1, lp, o_nC);
  gemm_nm<3><<<gg, 256, 0, stream>>>(o_nC, Wob, bo, x1, nullptr, (float*)d_out);
}